// Round 1
// baseline (6692.298 us; speedup 1.0000x reference)
//
#include <hip/hip_runtime.h>

typedef unsigned short u16;
typedef unsigned int u32;

#define NB 4
#define NVOX 8192
#define GD 50
#define PZ 52
#define CELLS 125000

// ---- workspace layout (bytes) ----
#define OWNER_OFF 0u            // int32[4*125000] = 2,000,000
#define STATS_OFF 2000000u      // f32[768] = 3072
#define WT1_OFF   2003072u      // bf16 27*64*128 = 442,368
#define WT2_OFF   2445440u      // bf16 27*128*64 = 442,368
#define GRID_OFF  2887808u      // bf16 4*50*50*52*128 = 133,120,000
#define Y1_OFF    136007808u    // bf16 4*50*50*52*64  =  66,560,000
// total ~202.6 MB

// stats f32 indices
#define S1_SUM 0
#define S1_SQ  64
#define SC1    128
#define SH1    192
#define S2_SUM 256
#define S2_SQ  384
#define SC2    512
#define SH2    640

__device__ __forceinline__ float bf2f(u16 v){ union{u32 u; float f;} x; x.u=((u32)v)<<16; return x.f; }
__device__ __forceinline__ u16 f2bf(float f){ union{u32 u; float f;} x; x.f=f; u32 r = x.u + 0x7fffu + ((x.u>>16)&1u); return (u16)(r>>16); }

// ---- weight re-layout: wt1[s][co][ci] (27,64,128), wt2[s][co][ci] (27,128,64), bf16 ----
__global__ void k_wt_transform(const float* __restrict__ k1, const float* __restrict__ k2,
                               u16* __restrict__ wt1, u16* __restrict__ wt2) {
    int idx = blockIdx.x * 256 + threadIdx.x;
    if (idx < 27*64*128) {
        int s = idx / (64*128); int r = idx % (64*128); int co = r >> 7; int ci = r & 127;
        wt1[idx] = f2bf(k1[(co*128 + ci)*27 + s]);
    }
    if (idx < 27*128*64) {
        int s = idx / (128*64); int r = idx % (128*64); int co = r >> 6; int ci = r & 63;
        wt2[idx] = f2bf(k2[(co*64 + ci)*27 + s]);
    }
}

// ---- duplicate resolution: last-write-wins == max n per cell ----
__global__ void k_owner(const int* __restrict__ coords, int* __restrict__ owner) {
    int v = blockIdx.x * 256 + threadIdx.x;
    if (v >= NB*NVOX) return;
    int b = v >> 13, n = v & (NVOX-1);
    int x = coords[v*3], y = coords[v*3+1], z = coords[v*3+2];
    atomicMax(&owner[b*CELLS + (x*GD + y)*GD + z], n);
}

// ---- VFE: per-voxel 3-layer MLP + max over 32 points, scatter to grid ----
__global__ __launch_bounds__(256) void k_vfe(
        const float* __restrict__ vf, const int* __restrict__ coords,
        const float* __restrict__ W1, const float* __restrict__ b1,
        const float* __restrict__ W2, const float* __restrict__ b2,
        const float* __restrict__ W3, const float* __restrict__ b3,
        const int* __restrict__ owner, u16* __restrict__ grid) {
    int v = blockIdx.x;
    int b = v >> 13, n = v & (NVOX-1);
    int t = threadIdx.x;
    __shared__ float xs[32][8];
    __shared__ float h1s[32][64];
    __shared__ float h2s[32][128];
    __shared__ float red[256];

    xs[t>>3][t&7] = vf[(size_t)v*256 + t];
    __syncthreads();
    { // h1 = relu(x@W1+b1): thread (c=t&63, pq=t>>6), p = pq+4i
        int c = t & 63, pq = t >> 6;
        float acc[8];
        #pragma unroll
        for (int i=0;i<8;i++) acc[i] = b1[c];
        #pragma unroll
        for (int k=0;k<8;k++) {
            float w = W1[k*64 + c];
            #pragma unroll
            for (int i=0;i<8;i++) acc[i] += xs[pq+4*i][k]*w;
        }
        #pragma unroll
        for (int i=0;i<8;i++) h1s[pq+4*i][c] = fmaxf(acc[i], 0.f);
    }
    __syncthreads();
    { // h2 = relu(h1@W2+b2): thread (c=t&127, ph=t>>7), 16 points
        int c = t & 127, ph = t >> 7;
        float acc[16];
        #pragma unroll
        for (int i=0;i<16;i++) acc[i] = b2[c];
        #pragma unroll 4
        for (int k=0;k<64;k++) {
            float w = W2[k*128 + c];
            #pragma unroll
            for (int i=0;i<16;i++) acc[i] += h1s[ph*16+i][k]*w;
        }
        #pragma unroll
        for (int i=0;i<16;i++) h2s[ph*16+i][c] = fmaxf(acc[i], 0.f);
    }
    __syncthreads();
    { // h3 = h2@W3 (+b3 after max); max over points
        int c = t & 127, ph = t >> 7;
        float acc[16];
        #pragma unroll
        for (int i=0;i<16;i++) acc[i] = 0.f;
        #pragma unroll 4
        for (int k=0;k<128;k++) {
            float w = W3[k*128 + c];
            #pragma unroll
            for (int i=0;i<16;i++) acc[i] += h2s[ph*16+i][k]*w;
        }
        float m = acc[0];
        #pragma unroll
        for (int i=1;i<16;i++) m = fmaxf(m, acc[i]);
        red[t] = m;
    }
    __syncthreads();
    if (t < 128) {
        float m = fmaxf(red[t], red[t+128]) + b3[t];
        int x = coords[v*3], y = coords[v*3+1], z = coords[v*3+2];
        if (owner[b*CELLS + (x*GD + y)*GD + z] == n) {
            size_t gi = ((((size_t)b*GD + x)*GD + y)*PZ + (z+1))*128 + t;
            grid[gi] = f2bf(m);
        }
    }
}

// ---- conv1: 3x3x3, 128->64, stride 1, pad 1. Raw output (pre-BN) + batch stats ----
__global__ __launch_bounds__(256) void k_conv1(
        const u16* __restrict__ grid, const u16* __restrict__ wt1,
        u16* __restrict__ y1, float* __restrict__ stats) {
    int ox = blockIdx.x, oy = blockIdx.y, b = blockIdx.z;
    int t = threadIdx.x;
    int co = t & 31, zg = t >> 5;           // 2 channels (co, co+32), 8 z-groups
    __shared__ __align__(16) u16 in_col[52*136];
    __shared__ __align__(16) u16 w_s[3*64*136];
    __shared__ float red[4*8*32];

    float acc_lo[7], acc_hi[7];
    int   zv[7]; bool val[7];
    #pragma unroll
    for (int i=0;i<7;i++) {
        acc_lo[i]=0.f; acc_hi[i]=0.f;
        int z = 1 + zg + 8*i; val[i] = (z <= 50); zv[i] = val[i] ? z : 49;
    }

    for (int dxy = 0; dxy < 9; ++dxy) {
        int dx = dxy/3, dy = dxy%3;
        int xi = ox + dx - 1, yi = oy + dy - 1;
        bool ok = (xi>=0 && xi<GD && yi>=0 && yi<GD);
        __syncthreads();
        { // stage input column (52 z rows x 128 ci), zero if out of range
            const u16* src = grid + (((size_t)b*GD + xi)*GD + yi)*(size_t)(PZ*128);
            for (int c8 = t; c8 < 832; c8 += 256) {
                int z = c8 >> 4, kc = c8 & 15;
                uint4 v = make_uint4(0u,0u,0u,0u);
                if (ok) v = *(const uint4*)&src[c8*8];
                *(uint4*)&in_col[z*136 + kc*8] = v;
            }
        }
        { // stage weights slice s = dxy*3 .. +3 : [3][64co][128ci] -> padded rows
            const u16* src = wt1 + (size_t)dxy*3*8192;
            for (int c8 = t; c8 < 3072; c8 += 256) {
                int dz = c8 >> 10, r = c8 & 1023;
                int cor = r >> 4, kc = r & 15;
                *(uint4*)&w_s[(dz*64 + cor)*136 + kc*8] = *(const uint4*)&src[c8*8];
            }
        }
        __syncthreads();
        for (int dz = 0; dz < 3; ++dz) {
            for (int kc = 0; kc < 16; ++kc) {
                float wl[8], wh[8];
                {
                    uint4 w4 = *(uint4*)&w_s[(dz*64 + co)*136 + kc*8];
                    const u16* p = (const u16*)&w4;
                    #pragma unroll
                    for (int j=0;j<8;j++) wl[j] = bf2f(p[j]);
                }
                {
                    uint4 w4 = *(uint4*)&w_s[(dz*64 + co + 32)*136 + kc*8];
                    const u16* p = (const u16*)&w4;
                    #pragma unroll
                    for (int j=0;j<8;j++) wh[j] = bf2f(p[j]);
                }
                #pragma unroll
                for (int i=0;i<7;i++) {
                    uint4 x4 = *(uint4*)&in_col[(zv[i]+dz-1)*136 + kc*8];
                    const u16* p = (const u16*)&x4;
                    #pragma unroll
                    for (int j=0;j<8;j++) {
                        float f = bf2f(p[j]);
                        acc_lo[i] += f*wl[j];
                        acc_hi[i] += f*wh[j];
                    }
                }
            }
        }
    }
    // store raw y1 + per-block stat partials (valid z only; invalid accs discarded)
    float s_lo=0.f, q_lo=0.f, s_hi=0.f, q_hi=0.f;
    #pragma unroll
    for (int i=0;i<7;i++) {
        if (val[i]) {
            int z = zv[i];
            s_lo += acc_lo[i]; q_lo += acc_lo[i]*acc_lo[i];
            s_hi += acc_hi[i]; q_hi += acc_hi[i]*acc_hi[i];
            size_t yb = ((((size_t)b*GD + ox)*GD + oy)*PZ + z)*64;
            y1[yb + co]      = f2bf(acc_lo[i]);
            y1[yb + co + 32] = f2bf(acc_hi[i]);
        }
    }
    red[(0*8+zg)*32+co] = s_lo;
    red[(1*8+zg)*32+co] = q_lo;
    red[(2*8+zg)*32+co] = s_hi;
    red[(3*8+zg)*32+co] = q_hi;
    __syncthreads();
    if (t < 64) {
        int cc = t & 31, base = (t < 32) ? 0 : 2;
        float s=0.f, q=0.f;
        #pragma unroll
        for (int g=0; g<8; ++g) {
            s += red[((base  )*8+g)*32+cc];
            q += red[((base+1)*8+g)*32+cc];
        }
        atomicAdd(&stats[S1_SUM + t], s);
        atomicAdd(&stats[S1_SQ  + t], q);
    }
}

// ---- BN finalize: scale/shift from sums ----
__global__ void k_finalize(float* __restrict__ stats, const float* __restrict__ g,
                           const float* __restrict__ be, int C, float cnt,
                           int st_off, int sc_off, int sh_off) {
    int t = threadIdx.x;
    if (t < C) {
        float mean = stats[st_off + t] / cnt;
        float var  = stats[st_off + C + t] / cnt - mean*mean;
        float inv  = rsqrtf(var + 1e-5f);
        stats[sc_off + t] = g[t]*inv;
        stats[sh_off + t] = be[t] - mean*g[t]*inv;
    }
}

// ---- conv2: 3x3x3, 64->128, stride 2, pad 1; BN1+ReLU fused into staging ----
__global__ __launch_bounds__(256) void k_conv2(
        const u16* __restrict__ y1, const u16* __restrict__ wt2,
        float* __restrict__ stats, float* __restrict__ out) {
    int ox = blockIdx.x, oy = blockIdx.y, b = blockIdx.z;
    int t = threadIdx.x;
    int co = t & 127, zg = t >> 7;
    __shared__ __align__(16) u16 in_col[52*72];
    __shared__ __align__(16) u16 w_s[3*128*72];
    __shared__ float red[2*2*128];
    const float* sc1 = stats + SC1;
    const float* sh1 = stats + SH1;

    float acc[13];
    #pragma unroll
    for (int i=0;i<13;i++) acc[i]=0.f;

    for (int dxy = 0; dxy < 9; ++dxy) {
        int dx = dxy/3, dy = dxy%3;
        int xi = 2*ox + dx - 1, yi = 2*oy + dy - 1;
        bool ok = (xi>=0 && xi<GD && yi>=0 && yi<GD);
        __syncthreads();
        { // stage BN1+ReLU'd input column (52 z x 64 ci); borders forced to 0
            const u16* src = y1 + (((size_t)b*GD + xi)*GD + yi)*(size_t)(PZ*64);
            for (int c8 = t; c8 < 416; c8 += 256) {
                int z = c8 >> 3, kc = c8 & 7;
                u16 dst8[8];
                bool zok = ok && (z >= 1) && (z <= 50);
                if (zok) {
                    uint4 v = *(const uint4*)&src[c8*8];
                    const u16* p = (const u16*)&v;
                    #pragma unroll
                    for (int j=0;j<8;j++) {
                        int ci = kc*8 + j;
                        dst8[j] = f2bf(fmaxf(bf2f(p[j])*sc1[ci] + sh1[ci], 0.f));
                    }
                } else {
                    #pragma unroll
                    for (int j=0;j<8;j++) dst8[j] = 0;
                }
                *(uint4*)&in_col[z*72 + kc*8] = *(uint4*)dst8;
            }
        }
        { // stage weights slice: [3][128co][64ci] padded rows
            const u16* src = wt2 + (size_t)dxy*3*8192;
            for (int c8 = t; c8 < 3072; c8 += 256) {
                int dz = c8 >> 10, r = c8 & 1023;
                int cor = r >> 3, kc = r & 7;
                *(uint4*)&w_s[(dz*128 + cor)*72 + kc*8] = *(const uint4*)&src[c8*8];
            }
        }
        __syncthreads();
        for (int dz = 0; dz < 3; ++dz) {
            for (int kc = 0; kc < 8; ++kc) {
                float wv[8];
                {
                    uint4 w4 = *(uint4*)&w_s[(dz*128 + co)*72 + kc*8];
                    const u16* p = (const u16*)&w4;
                    #pragma unroll
                    for (int j=0;j<8;j++) wv[j] = bf2f(p[j]);
                }
                #pragma unroll
                for (int i=0;i<13;i++) {
                    int oz = zg + 2*i;
                    if (oz <= 24) {
                        uint4 x4 = *(uint4*)&in_col[(2*oz + dz)*72 + kc*8];
                        const u16* p = (const u16*)&x4;
                        #pragma unroll
                        for (int j=0;j<8;j++) acc[i] += bf2f(p[j])*wv[j];
                    }
                }
            }
        }
    }
    // raw conv2 output to d_out (f32), stats partials
    float s=0.f, q=0.f;
    size_t ob = ((((size_t)b*128 + co)*25 + ox)*25 + oy)*25;
    #pragma unroll
    for (int i=0;i<13;i++) {
        int oz = zg + 2*i;
        if (oz <= 24) {
            s += acc[i]; q += acc[i]*acc[i];
            out[ob + oz] = acc[i];
        }
    }
    red[(0*2+zg)*128+co] = s;
    red[(1*2+zg)*128+co] = q;
    __syncthreads();
    if (t < 128) {
        float ss = red[(0*2+0)*128+t] + red[(0*2+1)*128+t];
        float qq = red[(1*2+0)*128+t] + red[(1*2+1)*128+t];
        atomicAdd(&stats[S2_SUM + t], ss);
        atomicAdd(&stats[S2_SQ  + t], qq);
    }
}

// ---- BN2 + ReLU applied in place on d_out ----
__global__ void k_bnrelu2(float* __restrict__ out, const float* __restrict__ stats) {
    int idx = blockIdx.x*256 + threadIdx.x;
    if (idx >= 8000000) return;
    int co = (idx / 15625) & 127;
    float v = out[idx];
    out[idx] = fmaxf(v*stats[SC2 + co] + stats[SH2 + co], 0.f);
}

extern "C" void kernel_launch(void* const* d_in, const int* in_sizes, int n_in,
                              void* d_out, int out_size, void* d_ws, size_t ws_size,
                              hipStream_t stream) {
    const float* vf     = (const float*)d_in[0];
    const int*   coords = (const int*)  d_in[1];
    const float* W1 = (const float*)d_in[2];
    const float* b1 = (const float*)d_in[3];
    const float* W2 = (const float*)d_in[4];
    const float* b2 = (const float*)d_in[5];
    const float* W3 = (const float*)d_in[6];
    const float* b3 = (const float*)d_in[7];
    const float* k1 = (const float*)d_in[8];
    const float* g1 = (const float*)d_in[9];
    const float* be1= (const float*)d_in[10];
    const float* k2 = (const float*)d_in[11];
    const float* g2 = (const float*)d_in[12];
    const float* be2= (const float*)d_in[13];

    char* ws = (char*)d_ws;
    int*   owner = (int*)  (ws + OWNER_OFF);
    float* stats = (float*)(ws + STATS_OFF);
    u16*   wt1   = (u16*)  (ws + WT1_OFF);
    u16*   wt2   = (u16*)  (ws + WT2_OFF);
    u16*   grid  = (u16*)  (ws + GRID_OFF);
    u16*   y1    = (u16*)  (ws + Y1_OFF);
    float* out   = (float*)d_out;

    hipMemsetAsync(owner, 0xFF, (size_t)NB*CELLS*4, stream);
    hipMemsetAsync(stats, 0, 768*4, stream);
    hipMemsetAsync(grid, 0, (size_t)NB*GD*GD*PZ*128*2, stream);

    k_wt_transform<<<864, 256, 0, stream>>>(k1, k2, wt1, wt2);
    k_owner<<<(NB*NVOX+255)/256, 256, 0, stream>>>(coords, owner);
    k_vfe<<<NB*NVOX, 256, 0, stream>>>(vf, coords, W1,b1,W2,b2,W3,b3, owner, grid);
    k_conv1<<<dim3(GD,GD,NB), 256, 0, stream>>>(grid, wt1, y1, stats);
    k_finalize<<<1, 64, 0, stream>>>(stats, g1, be1, 64, 500000.f, S1_SUM, SC1, SH1);
    k_conv2<<<dim3(25,25,NB), 256, 0, stream>>>(y1, wt2, stats, out);
    k_finalize<<<1, 128, 0, stream>>>(stats, g2, be2, 128, 62500.f, S2_SUM, SC2, SH2);
    k_bnrelu2<<<(8000000+255)/256, 256, 0, stream>>>(out, stats);
}

// Round 2
// 1577.398 us; speedup vs baseline: 4.2426x; 4.2426x over previous
//
#include <hip/hip_runtime.h>

typedef unsigned short u16;
typedef unsigned int u32;
typedef __attribute__((ext_vector_type(8))) short bf16x8;
typedef __attribute__((ext_vector_type(4))) float f32x4;

#define NB 4
#define NVOX 8192
#define GD 50
#define PZ 52
#define CELLS 125000

// ---- workspace layout (bytes) ----
#define OWNER_OFF 0u            // int32[4*125000] = 2,000,000
#define STATS_OFF 2000000u      // f32[768]
#define WT1_OFF   2003072u      // bf16 27*64*128 frag-linear = 442,368
#define WT2_OFF   2445440u      // bf16 27*128*64 frag-linear = 442,368
#define GRID_OFF  2887808u      // bf16 4*50*50*52*128 = 133,120,000
#define Y1_OFF    136007808u    // bf16 4*50*50*52*64  =  66,560,000

#define S1_SUM 0
#define S1_SQ  64
#define SC1    128
#define SH1    192
#define S2_SUM 256
#define S2_SQ  384
#define SC2    512
#define SH2    640

__device__ __forceinline__ float bf2f(u16 v){ union{u32 u; float f;} x; x.u=((u32)v)<<16; return x.f; }
__device__ __forceinline__ u16 f2bf(float f){ union{u32 u; float f;} x; x.f=f; u32 r = x.u + 0x7fffu + ((x.u>>16)&1u); return (u16)(r>>16); }
__device__ __forceinline__ f32x4 fzero(){ f32x4 v; v[0]=0.f; v[1]=0.f; v[2]=0.f; v[3]=0.f; return v; }

// ---- weight re-layout to MFMA frag-linear bf16 ----
// wt1: idx = (((s*4+kc)*4+kq)*64+co)*8+j ; ci = kc*32+kq*8+j ; s = dx*9+dy*3+dz
// wt2: idx = (((s*2+kc)*4+kq)*128+co)*8+j ; ci = kc*32+kq*8+j
__global__ void k_wt_transform(const float* __restrict__ k1, const float* __restrict__ k2,
                               u16* __restrict__ wt1, u16* __restrict__ wt2) {
    int idx = blockIdx.x * 256 + threadIdx.x;
    if (idx < 221184) {
        {
            int j = idx & 7, co = (idx>>3)&63, kq = (idx>>9)&3, kc = (idx>>11)&3, s = idx>>13;
            int ci = kc*32 + kq*8 + j;
            wt1[idx] = f2bf(k1[(co*128 + ci)*27 + s]);
        }
        {
            int j = idx & 7, co = (idx>>3)&127, kq = (idx>>10)&3, kc = (idx>>12)&1, s = idx>>13;
            int ci = kc*32 + kq*8 + j;
            wt2[idx] = f2bf(k2[(co*64 + ci)*27 + s]);
        }
    }
}

// ---- duplicate resolution: last-write-wins == max n per cell ----
__global__ void k_owner(const int* __restrict__ coords, int* __restrict__ owner) {
    int v = blockIdx.x * 256 + threadIdx.x;
    if (v >= NB*NVOX) return;
    int b = v >> 13, n = v & (NVOX-1);
    int x = coords[v*3], y = coords[v*3+1], z = coords[v*3+2];
    atomicMax(&owner[b*CELLS + (x*GD + y)*GD + z], n);
}

// ---- VFE: per-voxel 3-layer MLP + max over 32 points, scatter to grid ----
__global__ __launch_bounds__(256) void k_vfe(
        const float* __restrict__ vf, const int* __restrict__ coords,
        const float* __restrict__ W1, const float* __restrict__ b1,
        const float* __restrict__ W2, const float* __restrict__ b2,
        const float* __restrict__ W3, const float* __restrict__ b3,
        const int* __restrict__ owner, u16* __restrict__ grid) {
    int v = blockIdx.x;
    int b = v >> 13, n = v & (NVOX-1);
    int t = threadIdx.x;
    __shared__ float xs[32][8];
    __shared__ float h1s[32][64];
    __shared__ float h2s[32][128];
    __shared__ float red[256];

    xs[t>>3][t&7] = vf[(size_t)v*256 + t];
    __syncthreads();
    {
        int c = t & 63, pq = t >> 6;
        float acc[8];
        #pragma unroll
        for (int i=0;i<8;i++) acc[i] = b1[c];
        #pragma unroll
        for (int k=0;k<8;k++) {
            float w = W1[k*64 + c];
            #pragma unroll
            for (int i=0;i<8;i++) acc[i] += xs[pq+4*i][k]*w;
        }
        #pragma unroll
        for (int i=0;i<8;i++) h1s[pq+4*i][c] = fmaxf(acc[i], 0.f);
    }
    __syncthreads();
    {
        int c = t & 127, ph = t >> 7;
        float acc[16];
        #pragma unroll
        for (int i=0;i<16;i++) acc[i] = b2[c];
        #pragma unroll 4
        for (int k=0;k<64;k++) {
            float w = W2[k*128 + c];
            #pragma unroll
            for (int i=0;i<16;i++) acc[i] += h1s[ph*16+i][k]*w;
        }
        #pragma unroll
        for (int i=0;i<16;i++) h2s[ph*16+i][c] = fmaxf(acc[i], 0.f);
    }
    __syncthreads();
    {
        int c = t & 127, ph = t >> 7;
        float acc[16];
        #pragma unroll
        for (int i=0;i<16;i++) acc[i] = 0.f;
        #pragma unroll 4
        for (int k=0;k<128;k++) {
            float w = W3[k*128 + c];
            #pragma unroll
            for (int i=0;i<16;i++) acc[i] += h2s[ph*16+i][k]*w;
        }
        float m = acc[0];
        #pragma unroll
        for (int i=1;i<16;i++) m = fmaxf(m, acc[i]);
        red[t] = m;
    }
    __syncthreads();
    if (t < 128) {
        float m = fmaxf(red[t], red[t+128]) + b3[t];
        int x = coords[v*3], y = coords[v*3+1], z = coords[v*3+2];
        if (owner[b*CELLS + (x*GD + y)*GD + z] == n) {
            size_t gi = ((((size_t)b*GD + x)*GD + y)*PZ + (z+1))*128 + t;
            grid[gi] = f2bf(m);
        }
    }
}

// ---- conv1 via MFMA: 3x3x3, 128->64, stride 1, pad 1. Raw bf16 y1 + stats ----
// wg = (ox, oy-pair, b); wave w: col=w>>1, nh=w&1; wave tile = 64z x 32co
__global__ __launch_bounds__(256) void k_conv1(
        const u16* __restrict__ grid, const u16* __restrict__ wt1,
        u16* __restrict__ y1, float* __restrict__ stats) {
    const int ox = blockIdx.x, oyp = blockIdx.y, b = blockIdx.z;
    const int t = threadIdx.x;
    const int w = t >> 6, lane = t & 63;
    const int col = w >> 1, nh = w & 1, lo = lane & 15, hi = lane >> 4;

    __shared__ __align__(16) char pool[76288];
    u16* in_s = (u16*)pool;               // [2][52][128] bf16, slot^=(z&7) swizzled
    u16* w_s  = (u16*)(pool + 26624);     // [24576] frag-linear
    float* red = (float*)(pool + 75776);  // [128]
    if (t < 128) red[t] = 0.f;

    f32x4 acc[4][2];
    #pragma unroll
    for (int m=0;m<4;m++){ acc[m][0]=fzero(); acc[m][1]=fzero(); }

    for (int dxy = 0; dxy < 9; ++dxy) {
        int dx = dxy/3, dy = dxy - dx*3;
        int xi = ox + dx - 1;
        bool okx = (xi >= 0) && (xi < GD);
        __syncthreads();
        // stage 2 input columns, swizzled
        for (int i = t; i < 1664; i += 256) {
            int c = (i >= 832) ? 1 : 0;
            int cc = i - c*832;
            int z = cc >> 4, sl = cc & 15;
            int yi = 2*oyp + c + dy - 1;
            uint4 v = make_uint4(0u,0u,0u,0u);
            if (okx && yi >= 0 && yi < GD)
                v = *(const uint4*)(grid + (size_t)((b*GD + xi)*GD + yi)*6656 + cc*8);
            *(uint4*)(in_s + (c*52 + z)*128 + ((sl ^ (z & 7)) << 3)) = v;
        }
        // stage weights (frag-linear, conflict-free)
        {
            const u16* wsrc = wt1 + dxy*24576;
            #pragma unroll
            for (int i2 = 0; i2 < 12; ++i2) {
                int i = t + i2*256;
                *(uint4*)(w_s + i*8) = *(const uint4*)(wsrc + i*8);
            }
        }
        __syncthreads();
        #pragma unroll
        for (int dz = 0; dz < 3; ++dz) {
            #pragma unroll
            for (int kc = 0; kc < 4; ++kc) {
                bf16x8 a[4], bb[2];
                #pragma unroll
                for (int mf = 0; mf < 4; ++mf) {
                    int z = mf*16 + lo + dz; z = (z > 51) ? 51 : z;
                    a[mf] = *(const bf16x8*)(in_s + (col*52 + z)*128 + (((kc*4 + hi) ^ (z & 7)) << 3));
                }
                #pragma unroll
                for (int nf = 0; nf < 2; ++nf)
                    bb[nf] = *(const bf16x8*)(w_s + ((((dz*4 + kc)*4 + hi)*64) + (nh*2 + nf)*16 + lo)*8);
                #pragma unroll
                for (int mf = 0; mf < 4; ++mf) {
                    acc[mf][0] = __builtin_amdgcn_mfma_f32_16x16x32_bf16(a[mf], bb[0], acc[mf][0], 0, 0, 0);
                    acc[mf][1] = __builtin_amdgcn_mfma_f32_16x16x32_bf16(a[mf], bb[1], acc[mf][1], 0, 0, 0);
                }
            }
        }
    }
    // epilogue: store y1 (padded z index o+1) + stats partials
    const int oy = 2*oyp + col;
    const size_t colbase = ((size_t)(b*GD + ox)*GD + oy)*PZ;
    float s0=0.f,q0=0.f,s1=0.f,q1=0.f;
    #pragma unroll
    for (int mf = 0; mf < 4; ++mf) {
        #pragma unroll
        for (int r = 0; r < 4; ++r) {
            int o = mf*16 + hi*4 + r;
            if (o < 50) {
                float v0 = acc[mf][0][r], v1 = acc[mf][1][r];
                size_t rb = (colbase + o + 1)*64;
                y1[rb + nh*32 + lo]      = f2bf(v0);
                y1[rb + nh*32 + 16 + lo] = f2bf(v1);
                s0 += v0; q0 += v0*v0; s1 += v1; q1 += v1*v1;
            }
        }
    }
    atomicAdd(&red[nh*32 + lo], s0);
    atomicAdd(&red[64 + nh*32 + lo], q0);
    atomicAdd(&red[nh*32 + 16 + lo], s1);
    atomicAdd(&red[64 + nh*32 + 16 + lo], q1);
    // zero pad rows z=0, z=51 of both columns
    {
        int c2 = t >> 7, zs = (t >> 6) & 1, co = t & 63;
        size_t cb = ((size_t)(b*GD + ox)*GD + (2*oyp + c2))*PZ;
        y1[(cb + zs*51)*64 + co] = 0;
    }
    __syncthreads();
    if (t < 64) {
        atomicAdd(&stats[S1_SUM + t], red[t]);
        atomicAdd(&stats[S1_SQ  + t], red[64 + t]);
    }
}

// ---- BN finalize ----
__global__ void k_finalize(float* __restrict__ stats, const float* __restrict__ g,
                           const float* __restrict__ be, int C, float cnt,
                           int st_off, int sc_off, int sh_off) {
    int t = threadIdx.x;
    if (t < C) {
        float mean = stats[st_off + t] / cnt;
        float var  = stats[st_off + C + t] / cnt - mean*mean;
        float inv  = rsqrtf(var + 1e-5f);
        stats[sc_off + t] = g[t]*inv;
        stats[sh_off + t] = be[t] - mean*g[t]*inv;
    }
}

// ---- conv2 via MFMA: 3x3x3, 64->128, stride 2, pad 1; BN1+ReLU fused in staging ----
__global__ __launch_bounds__(256) void k_conv2(
        const u16* __restrict__ y1, const u16* __restrict__ wt2,
        float* __restrict__ stats, float* __restrict__ out) {
    const int ox = blockIdx.x, oyp = blockIdx.y, b = blockIdx.z;
    const int t = threadIdx.x;
    const int w = t >> 6, lane = t & 63;
    const int col = w >> 1, nh = w & 1, lo = lane & 15, hi = lane >> 4;

    __shared__ __align__(16) char pool[63488];
    u16* in2 = (u16*)pool;                // [2][52][64] bf16, slot^=((z>>1)&7)
    u16* w2s = (u16*)(pool + 13312);      // [24576] frag-linear
    float* red2 = (float*)(pool + 62464); // [256]
    red2[t] = 0.f;

    const float* sc1 = stats + SC1;
    const float* sh1 = stats + SH1;

    f32x4 acc[2][4];
    #pragma unroll
    for (int m=0;m<2;m++){ acc[m][0]=fzero(); acc[m][1]=fzero(); acc[m][2]=fzero(); acc[m][3]=fzero(); }

    const int oy = 2*oyp + col;   // may be 25 -> masked
    for (int dxy = 0; dxy < 9; ++dxy) {
        int dx = dxy/3, dy = dxy - dx*3;
        int xi = 2*ox + dx - 1;
        bool okx = (xi >= 0) && (xi < GD);
        __syncthreads();
        // stage BN1+ReLU'd input columns; borders forced to literal 0
        for (int i = t; i < 832; i += 256) {
            int c = (i >= 416) ? 1 : 0;
            int cc = i - c*416;
            int z = cc >> 3, sl = cc & 7;
            int oyc = 2*oyp + c;
            int yi = 2*oyc + dy - 1;
            bool ok = okx && (oyc < 25) && (yi >= 0) && (yi < GD) && (z >= 1) && (z <= 50);
            uint4 v = make_uint4(0u,0u,0u,0u);
            if (ok) v = *(const uint4*)(y1 + (size_t)((b*GD + xi)*GD + yi)*3328 + cc*8);
            const u16* p = (const u16*)&v;
            u16 d8[8];
            #pragma unroll
            for (int j=0;j<8;j++) {
                int ci = sl*8 + j;
                d8[j] = ok ? f2bf(fmaxf(bf2f(p[j])*sc1[ci] + sh1[ci], 0.f)) : (u16)0;
            }
            *(uint4*)(in2 + (c*52 + z)*64 + ((sl ^ ((z>>1) & 7)) << 3)) = *(uint4*)d8;
        }
        {
            const u16* wsrc = wt2 + dxy*24576;
            #pragma unroll
            for (int i2 = 0; i2 < 12; ++i2) {
                int i = t + i2*256;
                *(uint4*)(w2s + i*8) = *(const uint4*)(wsrc + i*8);
            }
        }
        __syncthreads();
        #pragma unroll
        for (int dz = 0; dz < 3; ++dz) {
            #pragma unroll
            for (int kc = 0; kc < 2; ++kc) {
                bf16x8 a[2], bb[4];
                #pragma unroll
                for (int mf = 0; mf < 2; ++mf) {
                    int z = 2*(mf*16 + lo) + dz; z = (z > 51) ? 51 : z;
                    a[mf] = *(const bf16x8*)(in2 + (col*52 + z)*64 + (((kc*4 + hi) ^ ((z>>1) & 7)) << 3));
                }
                #pragma unroll
                for (int nf = 0; nf < 4; ++nf)
                    bb[nf] = *(const bf16x8*)(w2s + (((dz*2 + kc)*4 + hi)*128 + (nh*4 + nf)*16 + lo)*8);
                #pragma unroll
                for (int mf = 0; mf < 2; ++mf) {
                    #pragma unroll
                    for (int nf = 0; nf < 4; ++nf)
                        acc[mf][nf] = __builtin_amdgcn_mfma_f32_16x16x32_bf16(a[mf], bb[nf], acc[mf][nf], 0, 0, 0);
                }
            }
        }
    }
    __syncthreads();                  // compute done -> reuse pool for transpose
    float* trans = (float*)pool;      // [2][128][25] f32 = 25600 B (< red2 offset)
    if (oy < 25) {
        #pragma unroll
        for (int nf = 0; nf < 4; ++nf) {
            float s = 0.f, q = 0.f;
            int co = (nh*4 + nf)*16 + lo;
            #pragma unroll
            for (int mf = 0; mf < 2; ++mf) {
                #pragma unroll
                for (int r = 0; r < 4; ++r) {
                    int o = mf*16 + hi*4 + r;
                    if (o < 25) {
                        float v = acc[mf][nf][r];
                        trans[(col*128 + co)*25 + o] = v;
                        s += v; q += v*v;
                    }
                }
            }
            atomicAdd(&red2[co], s);
            atomicAdd(&red2[128 + co], q);
        }
    }
    __syncthreads();
    if (t < 128) {
        atomicAdd(&stats[S2_SUM + t], red2[t]);
        atomicAdd(&stats[S2_SQ  + t], red2[128 + t]);
    }
    // coalesced raw store in final [b][co][x][y][z] layout
    for (int i = t; i < 6400; i += 256) {
        int c = i / 3200; int r = i - c*3200;
        int co = r / 25;  int oz = r - co*25;
        int oyc = 2*oyp + c;
        if (oyc < 25)
            out[((size_t)(b*128 + co)*625 + ox*25 + oyc)*25 + oz] = trans[(c*128 + co)*25 + oz];
    }
}

// ---- BN2 + ReLU in place on d_out ----
__global__ void k_bnrelu2(float* __restrict__ out, const float* __restrict__ stats) {
    int idx = blockIdx.x*256 + threadIdx.x;
    if (idx >= 8000000) return;
    int co = (idx / 15625) & 127;
    float v = out[idx];
    out[idx] = fmaxf(v*stats[SC2 + co] + stats[SH2 + co], 0.f);
}

extern "C" void kernel_launch(void* const* d_in, const int* in_sizes, int n_in,
                              void* d_out, int out_size, void* d_ws, size_t ws_size,
                              hipStream_t stream) {
    const float* vf     = (const float*)d_in[0];
    const int*   coords = (const int*)  d_in[1];
    const float* W1 = (const float*)d_in[2];
    const float* b1 = (const float*)d_in[3];
    const float* W2 = (const float*)d_in[4];
    const float* b2 = (const float*)d_in[5];
    const float* W3 = (const float*)d_in[6];
    const float* b3 = (const float*)d_in[7];
    const float* k1 = (const float*)d_in[8];
    const float* g1 = (const float*)d_in[9];
    const float* be1= (const float*)d_in[10];
    const float* k2 = (const float*)d_in[11];
    const float* g2 = (const float*)d_in[12];
    const float* be2= (const float*)d_in[13];

    char* ws = (char*)d_ws;
    int*   owner = (int*)  (ws + OWNER_OFF);
    float* stats = (float*)(ws + STATS_OFF);
    u16*   wt1   = (u16*)  (ws + WT1_OFF);
    u16*   wt2   = (u16*)  (ws + WT2_OFF);
    u16*   grid  = (u16*)  (ws + GRID_OFF);
    u16*   y1    = (u16*)  (ws + Y1_OFF);
    float* out   = (float*)d_out;

    hipMemsetAsync(owner, 0xFF, (size_t)NB*CELLS*4, stream);
    hipMemsetAsync(stats, 0, 768*4, stream);
    hipMemsetAsync(grid, 0, (size_t)NB*GD*GD*PZ*128*2, stream);

    k_wt_transform<<<864, 256, 0, stream>>>(k1, k2, wt1, wt2);
    k_owner<<<(NB*NVOX+255)/256, 256, 0, stream>>>(coords, owner);
    k_vfe<<<NB*NVOX, 256, 0, stream>>>(vf, coords, W1,b1,W2,b2,W3,b3, owner, grid);
    k_conv1<<<dim3(GD,25,NB), 256, 0, stream>>>(grid, wt1, y1, stats);
    k_finalize<<<1, 64, 0, stream>>>(stats, g1, be1, 64, 500000.f, S1_SUM, SC1, SH1);
    k_conv2<<<dim3(25,13,NB), 256, 0, stream>>>(y1, wt2, stats, out);
    k_finalize<<<1, 128, 0, stream>>>(stats, g2, be2, 128, 62500.f, S2_SUM, SC2, SH2);
    k_bnrelu2<<<(8000000+255)/256, 256, 0, stream>>>(out, stats);
}

// Round 3
// 857.771 us; speedup vs baseline: 7.8020x; 1.8390x over previous
//
#include <hip/hip_runtime.h>

typedef unsigned short u16;
typedef unsigned int u32;
typedef __attribute__((ext_vector_type(8))) short bf16x8;
typedef __attribute__((ext_vector_type(4))) float f32x4;

#define NB 4
#define NVOX 8192
#define GD 50
#define PZ 52
#define CELLS 125000

// ---- workspace layout (bytes) ----
#define OWNER_OFF 0u            // int32[4*125000] = 2,000,000
#define STATS_OFF 2000000u      // f32[768]
#define WT1_OFF   2003072u      // bf16 27*64*128 frag-linear = 442,368
#define WT2_OFF   2445440u      // bf16 27*128*64 frag-linear = 442,368
#define VW2F_OFF  2887808u      // bf16 8*128*8  = 16,384 (W2^T frag-linear)
#define VW3F_OFF  2904192u      // bf16 16*128*8 = 32,768 (W3^T frag-linear)
#define GRID_OFF  2936960u      // bf16 4*50*50*52*128 = 133,120,000
#define Y1_OFF    136056960u    // bf16 4*50*50*50*64  =  64,000,000  (no z-pad rows)
// end = 200,056,960 (< round-1's 202.5 MB footprint)

#define S1_SUM 0
#define S1_SQ  64
#define SC1    128
#define SH1    192
#define S2_SUM 256
#define S2_SQ  384
#define SC2    512
#define SH2    640

__device__ __forceinline__ float bf2f(u16 v){ union{u32 u; float f;} x; x.u=((u32)v)<<16; return x.f; }
__device__ __forceinline__ u16 f2bf(float f){ union{u32 u; float f;} x; x.f=f; u32 r = x.u + 0x7fffu + ((x.u>>16)&1u); return (u16)(r>>16); }
__device__ __forceinline__ f32x4 fzero(){ f32x4 v; v[0]=0.f; v[1]=0.f; v[2]=0.f; v[3]=0.f; return v; }

// ---- weight re-layout ----
// wt1:  idx = (((s*4+kc)*4+kq)*64+co)*8+j ; ci = kc*32+kq*8+j (conv1)
// wt2:  idx = (((s*2+kc)*4+kq)*128+co)*8+j ; ci = kc*32+kq*8+j (conv2)
// vw2f: idx = (q*128+n)*8+j ; holds W2[k=q*8+j][n]  (VFE layer2 A-frags)
// vw3f: idx = (q*128+n)*8+j ; holds W3[k=q*8+j][n]  (VFE layer3 A-frags)
__global__ void k_wt_transform(const float* __restrict__ k1, const float* __restrict__ k2,
                               const float* __restrict__ W2, const float* __restrict__ W3,
                               u16* __restrict__ wt1, u16* __restrict__ wt2,
                               u16* __restrict__ vw2f, u16* __restrict__ vw3f) {
    int idx = blockIdx.x * 256 + threadIdx.x;
    if (idx < 221184) {
        {
            int j = idx & 7, co = (idx>>3)&63, kq = (idx>>9)&3, kc = (idx>>11)&3, s = idx>>13;
            int ci = kc*32 + kq*8 + j;
            wt1[idx] = f2bf(k1[(co*128 + ci)*27 + s]);
        }
        {
            int j = idx & 7, co = (idx>>3)&127, kq = (idx>>10)&3, kc = (idx>>12)&1, s = idx>>13;
            int ci = kc*32 + kq*8 + j;
            wt2[idx] = f2bf(k2[(co*64 + ci)*27 + s]);
        }
    }
    if (idx < 8192) {
        int j = idx & 7, n = (idx>>3)&127, q = idx>>10;
        vw2f[idx] = f2bf(W2[(q*8+j)*128 + n]);
    }
    if (idx < 16384) {
        int j = idx & 7, n = (idx>>3)&127, q = idx>>10;
        vw3f[idx] = f2bf(W3[(q*8+j)*128 + n]);
    }
}

// ---- duplicate resolution: last-write-wins == max n per cell ----
__global__ void k_owner(const int* __restrict__ coords, int* __restrict__ owner) {
    int v = blockIdx.x * 256 + threadIdx.x;
    if (v >= NB*NVOX) return;
    int b = v >> 13, n = v & (NVOX-1);
    int x = coords[v*3], y = coords[v*3+1], z = coords[v*3+2];
    atomicMax(&owner[b*CELLS + (x*GD + y)*GD + z], n);
}

// ---- VFE via MFMA: 4 voxels (128 points) per block, 4 waves ----
// layer1 f32 VALU -> h1 bf16 LDS [pt][64] (k-contig, slot^=(pt&7))
// layer2 swapped MFMA: D2[ch][pt] = W2^T x h1 ; h2 -> LDS [pt][128] (slot^=(pt&15))
// layer3 swapped MFMA: D3[ch][pt] = W3^T x h2 ; max over pts via LDS reduce
__global__ __launch_bounds__(256, 2) void k_vfe(
        const float* __restrict__ vf, const int* __restrict__ coords,
        const float* __restrict__ W1, const float* __restrict__ b1,
        const float* __restrict__ b2, const float* __restrict__ b3,
        const u16* __restrict__ vw2f, const u16* __restrict__ vw3f,
        const int* __restrict__ owner, u16* __restrict__ grid) {
    const int bid = blockIdx.x;
    const int t = threadIdx.x;
    const int w = t >> 6, lane = t & 63;
    const int lo = lane & 15, hi = lane >> 4;
    const int chgrp = w >> 1, pgrp = w & 1;

    __shared__ __align__(16) char pool[49152];
    u16* h1s = (u16*)pool;                 // [128][64] bf16 swizzled
    char* h2s = pool + 16384;              // [128][128] bf16 swizzled (byte-addressed)
    float* red = (float*)(pool + 16384);   // [4 vox][16 lo][128 ch] f32 (reuses h2s)

    // ---- weight fragments into registers (issued early, consumed post-layer1) ----
    bf16x8 wa2[2][4], wa3[4][4];
    #pragma unroll
    for (int kk = 0; kk < 2; ++kk)
        #pragma unroll
        for (int cf = 0; cf < 4; ++cf)
            wa2[kk][cf] = *(const bf16x8*)(vw2f + (((kk*4+hi)*128) + chgrp*64 + cf*16 + lo)*8);
    #pragma unroll
    for (int kk = 0; kk < 4; ++kk)
        #pragma unroll
        for (int cf = 0; cf < 4; ++cf)
            wa3[kk][cf] = *(const bf16x8*)(vw3f + (((kk*4+hi)*128) + chgrp*64 + cf*16 + lo)*8);
    f32x4 bb2[4];
    #pragma unroll
    for (int cf = 0; cf < 4; ++cf)
        bb2[cf] = *(const f32x4*)(b2 + chgrp*64 + cf*16 + hi*4);

    // ---- layer1: f32, 2 threads per point (32 cols each) ----
    {
        const int pt = t & 127, C0 = (t >> 7) * 32;
        f32x4 xv0 = *(const f32x4*)(vf + (size_t)(bid*128 + pt)*8);
        f32x4 xv1 = *(const f32x4*)(vf + (size_t)(bid*128 + pt)*8 + 4);
        float x[8] = {xv0[0],xv0[1],xv0[2],xv0[3],xv1[0],xv1[1],xv1[2],xv1[3]};
        float h[32];
        #pragma unroll
        for (int c = 0; c < 32; ++c) h[c] = b1[C0 + c];
        #pragma unroll
        for (int k = 0; k < 8; ++k) {
            float xk = x[k];
            #pragma unroll
            for (int c = 0; c < 32; ++c) h[c] += xk * W1[k*64 + C0 + c];
        }
        #pragma unroll
        for (int c8 = 0; c8 < 4; ++c8) {
            u16 d8[8];
            #pragma unroll
            for (int j = 0; j < 8; ++j) d8[j] = f2bf(fmaxf(h[c8*8 + j], 0.f));
            int slot = ((C0 >> 3) + c8) ^ (pt & 7);
            *(uint4*)(h1s + pt*64 + slot*8) = *(uint4*)d8;
        }
    }
    __syncthreads();

    // ---- layer2: D2[ch][pt], K=64 ----
    f32x4 acc2[4][4];
    #pragma unroll
    for (int cf = 0; cf < 4; ++cf)
        #pragma unroll
        for (int pf = 0; pf < 4; ++pf) acc2[cf][pf] = fzero();
    #pragma unroll
    for (int kk = 0; kk < 2; ++kk) {
        bf16x8 bh[4];
        #pragma unroll
        for (int pf = 0; pf < 4; ++pf) {
            int pt = pgrp*64 + pf*16 + lo;
            bh[pf] = *(const bf16x8*)(h1s + pt*64 + (((kk*4+hi) ^ (pt&7)) << 3));
        }
        #pragma unroll
        for (int cf = 0; cf < 4; ++cf)
            #pragma unroll
            for (int pf = 0; pf < 4; ++pf)
                acc2[cf][pf] = __builtin_amdgcn_mfma_f32_16x16x32_bf16(wa2[kk][cf], bh[pf], acc2[cf][pf], 0, 0, 0);
    }
    // h2 = relu(acc2 + b2) -> LDS [pt][ch] (4 consecutive ch per lane -> b64)
    #pragma unroll
    for (int cf = 0; cf < 4; ++cf) {
        #pragma unroll
        for (int pf = 0; pf < 4; ++pf) {
            int pt = pgrp*64 + pf*16 + lo;
            float v0 = fmaxf(acc2[cf][pf][0] + bb2[cf][0], 0.f);
            float v1 = fmaxf(acc2[cf][pf][1] + bb2[cf][1], 0.f);
            float v2 = fmaxf(acc2[cf][pf][2] + bb2[cf][2], 0.f);
            float v3 = fmaxf(acc2[cf][pf][3] + bb2[cf][3], 0.f);
            uint2 d;
            d.x = (u32)f2bf(v0) | ((u32)f2bf(v1) << 16);
            d.y = (u32)f2bf(v2) | ((u32)f2bf(v3) << 16);
            int s = (chgrp*8 + cf*2 + (hi>>1)) ^ (pt & 15);
            *(uint2*)(h2s + pt*256 + s*16 + (hi&1)*8) = d;
        }
    }
    __syncthreads();

    // ---- layer3: D3[ch][pt], K=128 ----
    f32x4 acc3[4][4];
    #pragma unroll
    for (int cf = 0; cf < 4; ++cf)
        #pragma unroll
        for (int pf = 0; pf < 4; ++pf) acc3[cf][pf] = fzero();
    #pragma unroll
    for (int kk = 0; kk < 4; ++kk) {
        bf16x8 bh[4];
        #pragma unroll
        for (int pf = 0; pf < 4; ++pf) {
            int pt = pgrp*64 + pf*16 + lo;
            bh[pf] = *(const bf16x8*)(h2s + pt*256 + (((kk*4+hi) ^ (pt&15)) << 4));
        }
        #pragma unroll
        for (int cf = 0; cf < 4; ++cf)
            #pragma unroll
            for (int pf = 0; pf < 4; ++pf)
                acc3[cf][pf] = __builtin_amdgcn_mfma_f32_16x16x32_bf16(wa3[kk][cf], bh[pf], acc3[cf][pf], 0, 0, 0);
    }
    __syncthreads();   // all h2 reads done -> safe to overwrite with red

    // ---- per-lane partial max over point-frag pairs -> LDS ----
    #pragma unroll
    for (int vox01 = 0; vox01 < 2; ++vox01) {
        int vv = pgrp*2 + vox01;
        #pragma unroll
        for (int cf = 0; cf < 4; ++cf) {
            f32x4 mx;
            #pragma unroll
            for (int r = 0; r < 4; ++r)
                mx[r] = fmaxf(acc3[cf][vox01*2][r], acc3[cf][vox01*2+1][r]);
            int s4 = (cf*4 + hi) ^ lo;
            *(f32x4*)(red + vv*2048 + lo*128 + chgrp*64 + s4*4) = mx;
        }
    }
    __syncthreads();

    // ---- final reduce over 16 lanes + bias + owner-gated scatter ----
    #pragma unroll
    for (int half = 0; half < 2; ++half) {
        int vv = (t >> 7) + half*2;
        int ch = t & 127;
        int cq = (ch & 63) >> 2, e = ch & 3, cg = ch >> 6;
        float m = -3.0e38f;
        #pragma unroll
        for (int lo2 = 0; lo2 < 16; ++lo2)
            m = fmaxf(m, red[vv*2048 + lo2*128 + cg*64 + ((cq ^ lo2) << 2) + e]);
        int gv = bid*4 + vv;
        int b = gv >> 13, n = gv & (NVOX-1);
        int x = coords[gv*3], y = coords[gv*3+1], z = coords[gv*3+2];
        if (owner[b*CELLS + (x*GD + y)*GD + z] == n) {
            size_t gi = ((((size_t)b*GD + x)*GD + y)*PZ + (z+1))*128 + ch;
            grid[gi] = f2bf(m + b3[ch]);
        }
    }
}

// ---- conv1 via MFMA: 3x3x3, 128->64, stride 1, pad 1. Raw bf16 y1 + stats ----
__global__ __launch_bounds__(256) void k_conv1(
        const u16* __restrict__ grid, const u16* __restrict__ wt1,
        u16* __restrict__ y1, float* __restrict__ stats) {
    const int ox = blockIdx.x, oyp = blockIdx.y, b = blockIdx.z;
    const int t = threadIdx.x;
    const int w = t >> 6, lane = t & 63;
    const int col = w >> 1, nh = w & 1, lo = lane & 15, hi = lane >> 4;

    __shared__ __align__(16) char pool[76288];
    u16* in_s = (u16*)pool;               // [2][52][128] bf16, slot^=(z&7) swizzled
    u16* w_s  = (u16*)(pool + 26624);     // [24576] frag-linear
    float* red = (float*)(pool + 75776);  // [128]
    if (t < 128) red[t] = 0.f;

    f32x4 acc[4][2];
    #pragma unroll
    for (int m=0;m<4;m++){ acc[m][0]=fzero(); acc[m][1]=fzero(); }

    for (int dxy = 0; dxy < 9; ++dxy) {
        int dx = dxy/3, dy = dxy - dx*3;
        int xi = ox + dx - 1;
        bool okx = (xi >= 0) && (xi < GD);
        __syncthreads();
        for (int i = t; i < 1664; i += 256) {
            int c = (i >= 832) ? 1 : 0;
            int cc = i - c*832;
            int z = cc >> 4, sl = cc & 15;
            int yi = 2*oyp + c + dy - 1;
            uint4 v = make_uint4(0u,0u,0u,0u);
            if (okx && yi >= 0 && yi < GD)
                v = *(const uint4*)(grid + (size_t)((b*GD + xi)*GD + yi)*6656 + cc*8);
            *(uint4*)(in_s + (c*52 + z)*128 + ((sl ^ (z & 7)) << 3)) = v;
        }
        {
            const u16* wsrc = wt1 + dxy*24576;
            #pragma unroll
            for (int i2 = 0; i2 < 12; ++i2) {
                int i = t + i2*256;
                *(uint4*)(w_s + i*8) = *(const uint4*)(wsrc + i*8);
            }
        }
        __syncthreads();
        #pragma unroll
        for (int dz = 0; dz < 3; ++dz) {
            #pragma unroll
            for (int kc = 0; kc < 4; ++kc) {
                bf16x8 a[4], bb[2];
                #pragma unroll
                for (int mf = 0; mf < 4; ++mf) {
                    int z = mf*16 + lo + dz; z = (z > 51) ? 51 : z;
                    a[mf] = *(const bf16x8*)(in_s + (col*52 + z)*128 + (((kc*4 + hi) ^ (z & 7)) << 3));
                }
                #pragma unroll
                for (int nf = 0; nf < 2; ++nf)
                    bb[nf] = *(const bf16x8*)(w_s + ((((dz*4 + kc)*4 + hi)*64) + (nh*2 + nf)*16 + lo)*8);
                #pragma unroll
                for (int mf = 0; mf < 4; ++mf) {
                    acc[mf][0] = __builtin_amdgcn_mfma_f32_16x16x32_bf16(a[mf], bb[0], acc[mf][0], 0, 0, 0);
                    acc[mf][1] = __builtin_amdgcn_mfma_f32_16x16x32_bf16(a[mf], bb[1], acc[mf][1], 0, 0, 0);
                }
            }
        }
    }
    // epilogue: store y1 (z rows 0..49, stride 50) + stats partials
    const int oy = 2*oyp + col;
    const size_t colbase = ((size_t)(b*GD + ox)*GD + oy)*50;
    float s0=0.f,q0=0.f,s1=0.f,q1=0.f;
    #pragma unroll
    for (int mf = 0; mf < 4; ++mf) {
        #pragma unroll
        for (int r = 0; r < 4; ++r) {
            int o = mf*16 + hi*4 + r;
            if (o < 50) {
                float v0 = acc[mf][0][r], v1 = acc[mf][1][r];
                size_t rb = (colbase + o)*64;
                y1[rb + nh*32 + lo]      = f2bf(v0);
                y1[rb + nh*32 + 16 + lo] = f2bf(v1);
                s0 += v0; q0 += v0*v0; s1 += v1; q1 += v1*v1;
            }
        }
    }
    atomicAdd(&red[nh*32 + lo], s0);
    atomicAdd(&red[64 + nh*32 + lo], q0);
    atomicAdd(&red[nh*32 + 16 + lo], s1);
    atomicAdd(&red[64 + nh*32 + 16 + lo], q1);
    __syncthreads();
    if (t < 64) {
        atomicAdd(&stats[S1_SUM + t], red[t]);
        atomicAdd(&stats[S1_SQ  + t], red[64 + t]);
    }
}

// ---- BN finalize ----
__global__ void k_finalize(float* __restrict__ stats, const float* __restrict__ g,
                           const float* __restrict__ be, int C, float cnt,
                           int st_off, int sc_off, int sh_off) {
    int t = threadIdx.x;
    if (t < C) {
        float mean = stats[st_off + t] / cnt;
        float var  = stats[st_off + C + t] / cnt - mean*mean;
        float inv  = rsqrtf(var + 1e-5f);
        stats[sc_off + t] = g[t]*inv;
        stats[sh_off + t] = be[t] - mean*g[t]*inv;
    }
}

// ---- conv2 via MFMA: 3x3x3, 64->128, stride 2, pad 1; BN1+ReLU fused in staging ----
__global__ __launch_bounds__(256) void k_conv2(
        const u16* __restrict__ y1, const u16* __restrict__ wt2,
        float* __restrict__ stats, float* __restrict__ out) {
    const int ox = blockIdx.x, oyp = blockIdx.y, b = blockIdx.z;
    const int t = threadIdx.x;
    const int w = t >> 6, lane = t & 63;
    const int col = w >> 1, nh = w & 1, lo = lane & 15, hi = lane >> 4;

    __shared__ __align__(16) char pool[63488];
    u16* in2 = (u16*)pool;                // [2][52][64] bf16, slot^=((z>>1)&7)
    u16* w2s = (u16*)(pool + 13312);      // [24576] frag-linear
    float* red2 = (float*)(pool + 62464); // [256]
    red2[t] = 0.f;

    const float* sc1 = stats + SC1;
    const float* sh1 = stats + SH1;

    f32x4 acc[2][4];
    #pragma unroll
    for (int m=0;m<2;m++){ acc[m][0]=fzero(); acc[m][1]=fzero(); acc[m][2]=fzero(); acc[m][3]=fzero(); }

    const int oy = 2*oyp + col;   // may be 25 -> masked
    for (int dxy = 0; dxy < 9; ++dxy) {
        int dx = dxy/3, dy = dxy - dx*3;
        int xi = 2*ox + dx - 1;
        bool okx = (xi >= 0) && (xi < GD);
        __syncthreads();
        for (int i = t; i < 832; i += 256) {
            int c = (i >= 416) ? 1 : 0;
            int cc = i - c*416;
            int z = cc >> 3, sl = cc & 7;
            int oyc = 2*oyp + c;
            int yi = 2*oyc + dy - 1;
            bool ok = okx && (oyc < 25) && (yi >= 0) && (yi < GD) && (z >= 1) && (z <= 50);
            uint4 v = make_uint4(0u,0u,0u,0u);
            if (ok) v = *(const uint4*)(y1 + (size_t)((b*GD + xi)*GD + yi)*3200 + cc*8 - 64);
            const u16* p = (const u16*)&v;
            u16 d8[8];
            #pragma unroll
            for (int j=0;j<8;j++) {
                int ci = sl*8 + j;
                d8[j] = ok ? f2bf(fmaxf(bf2f(p[j])*sc1[ci] + sh1[ci], 0.f)) : (u16)0;
            }
            *(uint4*)(in2 + (c*52 + z)*64 + ((sl ^ ((z>>1) & 7)) << 3)) = *(uint4*)d8;
        }
        {
            const u16* wsrc = wt2 + dxy*24576;
            #pragma unroll
            for (int i2 = 0; i2 < 12; ++i2) {
                int i = t + i2*256;
                *(uint4*)(w2s + i*8) = *(const uint4*)(wsrc + i*8);
            }
        }
        __syncthreads();
        #pragma unroll
        for (int dz = 0; dz < 3; ++dz) {
            #pragma unroll
            for (int kc = 0; kc < 2; ++kc) {
                bf16x8 a[2], bb[4];
                #pragma unroll
                for (int mf = 0; mf < 2; ++mf) {
                    int z = 2*(mf*16 + lo) + dz; z = (z > 51) ? 51 : z;
                    a[mf] = *(const bf16x8*)(in2 + (col*52 + z)*64 + (((kc*4 + hi) ^ ((z>>1) & 7)) << 3));
                }
                #pragma unroll
                for (int nf = 0; nf < 4; ++nf)
                    bb[nf] = *(const bf16x8*)(w2s + (((dz*2 + kc)*4 + hi)*128 + (nh*4 + nf)*16 + lo)*8);
                #pragma unroll
                for (int mf = 0; mf < 2; ++mf) {
                    #pragma unroll
                    for (int nf = 0; nf < 4; ++nf)
                        acc[mf][nf] = __builtin_amdgcn_mfma_f32_16x16x32_bf16(a[mf], bb[nf], acc[mf][nf], 0, 0, 0);
                }
            }
        }
    }
    __syncthreads();                  // compute done -> reuse pool for transpose
    float* trans = (float*)pool;      // [2][128][25] f32 = 25600 B
    if (oy < 25) {
        #pragma unroll
        for (int nf = 0; nf < 4; ++nf) {
            float s = 0.f, q = 0.f;
            int co = (nh*4 + nf)*16 + lo;
            #pragma unroll
            for (int mf = 0; mf < 2; ++mf) {
                #pragma unroll
                for (int r = 0; r < 4; ++r) {
                    int o = mf*16 + hi*4 + r;
                    if (o < 25) {
                        float v = acc[mf][nf][r];
                        trans[(col*128 + co)*25 + o] = v;
                        s += v; q += v*v;
                    }
                }
            }
            atomicAdd(&red2[co], s);
            atomicAdd(&red2[128 + co], q);
        }
    }
    __syncthreads();
    if (t < 128) {
        atomicAdd(&stats[S2_SUM + t], red2[t]);
        atomicAdd(&stats[S2_SQ  + t], red2[128 + t]);
    }
    for (int i = t; i < 6400; i += 256) {
        int c = i / 3200; int r = i - c*3200;
        int co = r / 25;  int oz = r - co*25;
        int oyc = 2*oyp + c;
        if (oyc < 25)
            out[((size_t)(b*128 + co)*625 + ox*25 + oyc)*25 + oz] = trans[(c*128 + co)*25 + oz];
    }
}

// ---- BN2 + ReLU in place on d_out ----
__global__ void k_bnrelu2(float* __restrict__ out, const float* __restrict__ stats) {
    int idx = blockIdx.x*256 + threadIdx.x;
    if (idx >= 8000000) return;
    int co = (idx / 15625) & 127;
    float v = out[idx];
    out[idx] = fmaxf(v*stats[SC2 + co] + stats[SH2 + co], 0.f);
}

extern "C" void kernel_launch(void* const* d_in, const int* in_sizes, int n_in,
                              void* d_out, int out_size, void* d_ws, size_t ws_size,
                              hipStream_t stream) {
    const float* vf     = (const float*)d_in[0];
    const int*   coords = (const int*)  d_in[1];
    const float* W1 = (const float*)d_in[2];
    const float* b1 = (const float*)d_in[3];
    const float* W2 = (const float*)d_in[4];
    const float* b2 = (const float*)d_in[5];
    const float* W3 = (const float*)d_in[6];
    const float* b3 = (const float*)d_in[7];
    const float* k1 = (const float*)d_in[8];
    const float* g1 = (const float*)d_in[9];
    const float* be1= (const float*)d_in[10];
    const float* k2 = (const float*)d_in[11];
    const float* g2 = (const float*)d_in[12];
    const float* be2= (const float*)d_in[13];

    char* ws = (char*)d_ws;
    int*   owner = (int*)  (ws + OWNER_OFF);
    float* stats = (float*)(ws + STATS_OFF);
    u16*   wt1   = (u16*)  (ws + WT1_OFF);
    u16*   wt2   = (u16*)  (ws + WT2_OFF);
    u16*   vw2f  = (u16*)  (ws + VW2F_OFF);
    u16*   vw3f  = (u16*)  (ws + VW3F_OFF);
    u16*   grid  = (u16*)  (ws + GRID_OFF);
    u16*   y1    = (u16*)  (ws + Y1_OFF);
    float* out   = (float*)d_out;

    hipMemsetAsync(owner, 0xFF, (size_t)NB*CELLS*4, stream);
    hipMemsetAsync(stats, 0, 768*4, stream);
    hipMemsetAsync(grid, 0, (size_t)NB*GD*GD*PZ*128*2, stream);

    k_wt_transform<<<864, 256, 0, stream>>>(k1, k2, W2, W3, wt1, wt2, vw2f, vw3f);
    k_owner<<<(NB*NVOX+255)/256, 256, 0, stream>>>(coords, owner);
    k_vfe<<<NB*NVOX/4, 256, 0, stream>>>(vf, coords, W1, b1, b2, b3, vw2f, vw3f, owner, grid);
    k_conv1<<<dim3(GD,25,NB), 256, 0, stream>>>(grid, wt1, y1, stats);
    k_finalize<<<1, 64, 0, stream>>>(stats, g1, be1, 64, 500000.f, S1_SUM, SC1, SH1);
    k_conv2<<<dim3(25,13,NB), 256, 0, stream>>>(y1, wt2, stats, out);
    k_finalize<<<1, 128, 0, stream>>>(stats, g2, be2, 128, 62500.f, S2_SUM, SC2, SH2);
    k_bnrelu2<<<(8000000+255)/256, 256, 0, stream>>>(out, stats);
}

// Round 4
// 849.545 us; speedup vs baseline: 7.8775x; 1.0097x over previous
//
#include <hip/hip_runtime.h>

typedef unsigned short u16;
typedef unsigned int u32;
typedef __attribute__((ext_vector_type(8))) short bf16x8;
typedef __attribute__((ext_vector_type(4))) float f32x4;

#define NB 4
#define NVOX 8192
#define GD 50
#define PZ 52
#define CELLS 125000

// ---- workspace layout (bytes) ----
#define OWNER_OFF 0u            // int32[4*125000] = 2,000,000
#define STATS_OFF 2000000u      // f32[768]
#define WT1_OFF   2003072u      // bf16 27*64*128 frag-linear = 442,368
#define WT2_OFF   2445440u      // bf16 27*128*64 frag-linear = 442,368
#define VW2F_OFF  2887808u      // bf16 8*128*8  = 16,384 (W2^T frag-linear)
#define VW3F_OFF  2904192u      // bf16 16*128*8 = 32,768 (W3^T frag-linear)
#define GRID_OFF  2936960u      // bf16 4*50*50*52*128 = 133,120,000
#define Y1_OFF    136056960u    // bf16 4*50*50*50*64  =  64,000,000  (no z-pad rows)

#define S1_SUM 0
#define S1_SQ  64
#define SC1    128
#define SH1    192
#define S2_SUM 256
#define S2_SQ  384
#define SC2    512
#define SH2    640

__device__ __forceinline__ float bf2f(u16 v){ union{u32 u; float f;} x; x.u=((u32)v)<<16; return x.f; }
__device__ __forceinline__ u16 f2bf(float f){ union{u32 u; float f;} x; x.f=f; u32 r = x.u + 0x7fffu + ((x.u>>16)&1u); return (u16)(r>>16); }
__device__ __forceinline__ f32x4 fzero(){ f32x4 v; v[0]=0.f; v[1]=0.f; v[2]=0.f; v[3]=0.f; return v; }

// ---- weight re-layout ----
__global__ void k_wt_transform(const float* __restrict__ k1, const float* __restrict__ k2,
                               const float* __restrict__ W2, const float* __restrict__ W3,
                               u16* __restrict__ wt1, u16* __restrict__ wt2,
                               u16* __restrict__ vw2f, u16* __restrict__ vw3f) {
    int idx = blockIdx.x * 256 + threadIdx.x;
    if (idx < 221184) {
        {
            int j = idx & 7, co = (idx>>3)&63, kq = (idx>>9)&3, kc = (idx>>11)&3, s = idx>>13;
            int ci = kc*32 + kq*8 + j;
            wt1[idx] = f2bf(k1[(co*128 + ci)*27 + s]);
        }
        {
            int j = idx & 7, co = (idx>>3)&127, kq = (idx>>10)&3, kc = (idx>>12)&1, s = idx>>13;
            int ci = kc*32 + kq*8 + j;
            wt2[idx] = f2bf(k2[(co*64 + ci)*27 + s]);
        }
    }
    if (idx < 8192) {
        int j = idx & 7, n = (idx>>3)&127, q = idx>>10;
        vw2f[idx] = f2bf(W2[(q*8+j)*128 + n]);
    }
    if (idx < 16384) {
        int j = idx & 7, n = (idx>>3)&127, q = idx>>10;
        vw3f[idx] = f2bf(W3[(q*8+j)*128 + n]);
    }
}

// ---- duplicate resolution: last-write-wins == max n per cell ----
__global__ void k_owner(const int* __restrict__ coords, int* __restrict__ owner) {
    int v = blockIdx.x * 256 + threadIdx.x;
    if (v >= NB*NVOX) return;
    int b = v >> 13, n = v & (NVOX-1);
    int x = coords[v*3], y = coords[v*3+1], z = coords[v*3+2];
    atomicMax(&owner[b*CELLS + (x*GD + y)*GD + z], n);
}

// ---- VFE via MFMA: 4 voxels (128 points) per block, 4 waves ----
__global__ __launch_bounds__(256, 2) void k_vfe(
        const float* __restrict__ vf, const int* __restrict__ coords,
        const float* __restrict__ W1, const float* __restrict__ b1,
        const float* __restrict__ b2, const float* __restrict__ b3,
        const u16* __restrict__ vw2f, const u16* __restrict__ vw3f,
        const int* __restrict__ owner, u16* __restrict__ grid) {
    const int bid = blockIdx.x;
    const int t = threadIdx.x;
    const int w = t >> 6, lane = t & 63;
    const int lo = lane & 15, hi = lane >> 4;
    const int chgrp = w >> 1, pgrp = w & 1;

    __shared__ __align__(16) char pool[49152];
    u16* h1s = (u16*)pool;                 // [128][64] bf16 swizzled
    char* h2s = pool + 16384;              // [128][128] bf16 swizzled (byte-addressed)
    float* red = (float*)(pool + 16384);   // [4 vox][16 lo][128 ch] f32 (reuses h2s)

    bf16x8 wa2[2][4], wa3[4][4];
    #pragma unroll
    for (int kk = 0; kk < 2; ++kk)
        #pragma unroll
        for (int cf = 0; cf < 4; ++cf)
            wa2[kk][cf] = *(const bf16x8*)(vw2f + (((kk*4+hi)*128) + chgrp*64 + cf*16 + lo)*8);
    #pragma unroll
    for (int kk = 0; kk < 4; ++kk)
        #pragma unroll
        for (int cf = 0; cf < 4; ++cf)
            wa3[kk][cf] = *(const bf16x8*)(vw3f + (((kk*4+hi)*128) + chgrp*64 + cf*16 + lo)*8);
    f32x4 bb2[4];
    #pragma unroll
    for (int cf = 0; cf < 4; ++cf)
        bb2[cf] = *(const f32x4*)(b2 + chgrp*64 + cf*16 + hi*4);

    {
        const int pt = t & 127, C0 = (t >> 7) * 32;
        f32x4 xv0 = *(const f32x4*)(vf + (size_t)(bid*128 + pt)*8);
        f32x4 xv1 = *(const f32x4*)(vf + (size_t)(bid*128 + pt)*8 + 4);
        float x[8] = {xv0[0],xv0[1],xv0[2],xv0[3],xv1[0],xv1[1],xv1[2],xv1[3]};
        float h[32];
        #pragma unroll
        for (int c = 0; c < 32; ++c) h[c] = b1[C0 + c];
        #pragma unroll
        for (int k = 0; k < 8; ++k) {
            float xk = x[k];
            #pragma unroll
            for (int c = 0; c < 32; ++c) h[c] += xk * W1[k*64 + C0 + c];
        }
        #pragma unroll
        for (int c8 = 0; c8 < 4; ++c8) {
            u16 d8[8];
            #pragma unroll
            for (int j = 0; j < 8; ++j) d8[j] = f2bf(fmaxf(h[c8*8 + j], 0.f));
            int slot = ((C0 >> 3) + c8) ^ (pt & 7);
            *(uint4*)(h1s + pt*64 + slot*8) = *(uint4*)d8;
        }
    }
    __syncthreads();

    f32x4 acc2[4][4];
    #pragma unroll
    for (int cf = 0; cf < 4; ++cf)
        #pragma unroll
        for (int pf = 0; pf < 4; ++pf) acc2[cf][pf] = fzero();
    #pragma unroll
    for (int kk = 0; kk < 2; ++kk) {
        bf16x8 bh[4];
        #pragma unroll
        for (int pf = 0; pf < 4; ++pf) {
            int pt = pgrp*64 + pf*16 + lo;
            bh[pf] = *(const bf16x8*)(h1s + pt*64 + (((kk*4+hi) ^ (pt&7)) << 3));
        }
        #pragma unroll
        for (int cf = 0; cf < 4; ++cf)
            #pragma unroll
            for (int pf = 0; pf < 4; ++pf)
                acc2[cf][pf] = __builtin_amdgcn_mfma_f32_16x16x32_bf16(wa2[kk][cf], bh[pf], acc2[cf][pf], 0, 0, 0);
    }
    #pragma unroll
    for (int cf = 0; cf < 4; ++cf) {
        #pragma unroll
        for (int pf = 0; pf < 4; ++pf) {
            int pt = pgrp*64 + pf*16 + lo;
            float v0 = fmaxf(acc2[cf][pf][0] + bb2[cf][0], 0.f);
            float v1 = fmaxf(acc2[cf][pf][1] + bb2[cf][1], 0.f);
            float v2 = fmaxf(acc2[cf][pf][2] + bb2[cf][2], 0.f);
            float v3 = fmaxf(acc2[cf][pf][3] + bb2[cf][3], 0.f);
            uint2 d;
            d.x = (u32)f2bf(v0) | ((u32)f2bf(v1) << 16);
            d.y = (u32)f2bf(v2) | ((u32)f2bf(v3) << 16);
            int s = (chgrp*8 + cf*2 + (hi>>1)) ^ (pt & 15);
            *(uint2*)(h2s + pt*256 + s*16 + (hi&1)*8) = d;
        }
    }
    __syncthreads();

    f32x4 acc3[4][4];
    #pragma unroll
    for (int cf = 0; cf < 4; ++cf)
        #pragma unroll
        for (int pf = 0; pf < 4; ++pf) acc3[cf][pf] = fzero();
    #pragma unroll
    for (int kk = 0; kk < 4; ++kk) {
        bf16x8 bh[4];
        #pragma unroll
        for (int pf = 0; pf < 4; ++pf) {
            int pt = pgrp*64 + pf*16 + lo;
            bh[pf] = *(const bf16x8*)(h2s + pt*256 + (((kk*4+hi) ^ (pt&15)) << 4));
        }
        #pragma unroll
        for (int cf = 0; cf < 4; ++cf)
            #pragma unroll
            for (int pf = 0; pf < 4; ++pf)
                acc3[cf][pf] = __builtin_amdgcn_mfma_f32_16x16x32_bf16(wa3[kk][cf], bh[pf], acc3[cf][pf], 0, 0, 0);
    }
    __syncthreads();

    #pragma unroll
    for (int vox01 = 0; vox01 < 2; ++vox01) {
        int vv = pgrp*2 + vox01;
        #pragma unroll
        for (int cf = 0; cf < 4; ++cf) {
            f32x4 mx;
            #pragma unroll
            for (int r = 0; r < 4; ++r)
                mx[r] = fmaxf(acc3[cf][vox01*2][r], acc3[cf][vox01*2+1][r]);
            int s4 = (cf*4 + hi) ^ lo;
            *(f32x4*)(red + vv*2048 + lo*128 + chgrp*64 + s4*4) = mx;
        }
    }
    __syncthreads();

    #pragma unroll
    for (int half = 0; half < 2; ++half) {
        int vv = (t >> 7) + half*2;
        int ch = t & 127;
        int cq = (ch & 63) >> 2, e = ch & 3, cg = ch >> 6;
        float m = -3.0e38f;
        #pragma unroll
        for (int lo2 = 0; lo2 < 16; ++lo2)
            m = fmaxf(m, red[vv*2048 + lo2*128 + cg*64 + ((cq ^ lo2) << 2) + e]);
        int gv = bid*4 + vv;
        int b = gv >> 13, n = gv & (NVOX-1);
        int x = coords[gv*3], y = coords[gv*3+1], z = coords[gv*3+2];
        if (owner[b*CELLS + (x*GD + y)*GD + z] == n) {
            size_t gi = ((((size_t)b*GD + x)*GD + y)*PZ + (z+1))*128 + ch;
            grid[gi] = f2bf(m + b3[ch]);
        }
    }
}

// ---- conv1 via MFMA: 3x3x3, 128->64, stride 1, pad 1. Raw bf16 y1 + stats ----
// 4-bit XOR swizzle on in_s: z-rows stride 256B (bank-aliased); slot^(z&15)
// spreads the 16-row A-frag read across all 16 slots -> 2-way residual (free).
__global__ __launch_bounds__(256) void k_conv1(
        const u16* __restrict__ grid, const u16* __restrict__ wt1,
        u16* __restrict__ y1, float* __restrict__ stats) {
    const int ox = blockIdx.x, oyp = blockIdx.y, b = blockIdx.z;
    const int t = threadIdx.x;
    const int w = t >> 6, lane = t & 63;
    const int col = w >> 1, nh = w & 1, lo = lane & 15, hi = lane >> 4;

    __shared__ __align__(16) char pool[76288];
    u16* in_s = (u16*)pool;               // [2][52][128] bf16, slot^=(z&15) swizzled
    u16* w_s  = (u16*)(pool + 26624);     // [24576] frag-linear
    float* red = (float*)(pool + 75776);  // [128]
    if (t < 128) red[t] = 0.f;

    f32x4 acc[4][2];
    #pragma unroll
    for (int m=0;m<4;m++){ acc[m][0]=fzero(); acc[m][1]=fzero(); }

    for (int dxy = 0; dxy < 9; ++dxy) {
        int dx = dxy/3, dy = dxy - dx*3;
        int xi = ox + dx - 1;
        bool okx = (xi >= 0) && (xi < GD);
        __syncthreads();
        for (int i = t; i < 1664; i += 256) {
            int c = (i >= 832) ? 1 : 0;
            int cc = i - c*832;
            int z = cc >> 4, sl = cc & 15;
            int yi = 2*oyp + c + dy - 1;
            uint4 v = make_uint4(0u,0u,0u,0u);
            if (okx && yi >= 0 && yi < GD)
                v = *(const uint4*)(grid + (size_t)((b*GD + xi)*GD + yi)*6656 + cc*8);
            *(uint4*)(in_s + (c*52 + z)*128 + ((sl ^ (z & 15)) << 3)) = v;
        }
        {
            const u16* wsrc = wt1 + dxy*24576;
            #pragma unroll
            for (int i2 = 0; i2 < 12; ++i2) {
                int i = t + i2*256;
                *(uint4*)(w_s + i*8) = *(const uint4*)(wsrc + i*8);
            }
        }
        __syncthreads();
        #pragma unroll
        for (int dz = 0; dz < 3; ++dz) {
            #pragma unroll
            for (int kc = 0; kc < 4; ++kc) {
                bf16x8 a[4], bb[2];
                #pragma unroll
                for (int mf = 0; mf < 4; ++mf) {
                    int z = mf*16 + lo + dz; z = (z > 51) ? 51 : z;
                    a[mf] = *(const bf16x8*)(in_s + (col*52 + z)*128 + (((kc*4 + hi) ^ (z & 15)) << 3));
                }
                #pragma unroll
                for (int nf = 0; nf < 2; ++nf)
                    bb[nf] = *(const bf16x8*)(w_s + ((((dz*4 + kc)*4 + hi)*64) + (nh*2 + nf)*16 + lo)*8);
                #pragma unroll
                for (int mf = 0; mf < 4; ++mf) {
                    acc[mf][0] = __builtin_amdgcn_mfma_f32_16x16x32_bf16(a[mf], bb[0], acc[mf][0], 0, 0, 0);
                    acc[mf][1] = __builtin_amdgcn_mfma_f32_16x16x32_bf16(a[mf], bb[1], acc[mf][1], 0, 0, 0);
                }
            }
        }
    }
    const int oy = 2*oyp + col;
    const size_t colbase = ((size_t)(b*GD + ox)*GD + oy)*50;
    float s0=0.f,q0=0.f,s1=0.f,q1=0.f;
    #pragma unroll
    for (int mf = 0; mf < 4; ++mf) {
        #pragma unroll
        for (int r = 0; r < 4; ++r) {
            int o = mf*16 + hi*4 + r;
            if (o < 50) {
                float v0 = acc[mf][0][r], v1 = acc[mf][1][r];
                size_t rb = (colbase + o)*64;
                y1[rb + nh*32 + lo]      = f2bf(v0);
                y1[rb + nh*32 + 16 + lo] = f2bf(v1);
                s0 += v0; q0 += v0*v0; s1 += v1; q1 += v1*v1;
            }
        }
    }
    atomicAdd(&red[nh*32 + lo], s0);
    atomicAdd(&red[64 + nh*32 + lo], q0);
    atomicAdd(&red[nh*32 + 16 + lo], s1);
    atomicAdd(&red[64 + nh*32 + 16 + lo], q1);
    __syncthreads();
    if (t < 64) {
        atomicAdd(&stats[S1_SUM + t], red[t]);
        atomicAdd(&stats[S1_SQ  + t], red[64 + t]);
    }
}

// ---- BN finalize ----
__global__ void k_finalize(float* __restrict__ stats, const float* __restrict__ g,
                           const float* __restrict__ be, int C, float cnt,
                           int st_off, int sc_off, int sh_off) {
    int t = threadIdx.x;
    if (t < C) {
        float mean = stats[st_off + t] / cnt;
        float var  = stats[st_off + C + t] / cnt - mean*mean;
        float inv  = rsqrtf(var + 1e-5f);
        stats[sc_off + t] = g[t]*inv;
        stats[sh_off + t] = be[t] - mean*g[t]*inv;
    }
}

// ---- conv2 via MFMA: 3x3x3, 64->128, stride 2, pad 1; BN1+ReLU fused in staging ----
__global__ __launch_bounds__(256) void k_conv2(
        const u16* __restrict__ y1, const u16* __restrict__ wt2,
        float* __restrict__ stats, float* __restrict__ out) {
    const int ox = blockIdx.x, oyp = blockIdx.y, b = blockIdx.z;
    const int t = threadIdx.x;
    const int w = t >> 6, lane = t & 63;
    const int col = w >> 1, nh = w & 1, lo = lane & 15, hi = lane >> 4;

    __shared__ __align__(16) char pool[63488];
    u16* in2 = (u16*)pool;                // [2][52][64] bf16, slot^=((z>>1)&7)
    u16* w2s = (u16*)(pool + 13312);      // [24576] frag-linear
    float* red2 = (float*)(pool + 62464); // [256]
    red2[t] = 0.f;

    const float* sc1 = stats + SC1;
    const float* sh1 = stats + SH1;

    f32x4 acc[2][4];
    #pragma unroll
    for (int m=0;m<2;m++){ acc[m][0]=fzero(); acc[m][1]=fzero(); acc[m][2]=fzero(); acc[m][3]=fzero(); }

    const int oy = 2*oyp + col;
    for (int dxy = 0; dxy < 9; ++dxy) {
        int dx = dxy/3, dy = dxy - dx*3;
        int xi = 2*ox + dx - 1;
        bool okx = (xi >= 0) && (xi < GD);
        __syncthreads();
        for (int i = t; i < 832; i += 256) {
            int c = (i >= 416) ? 1 : 0;
            int cc = i - c*416;
            int z = cc >> 3, sl = cc & 7;
            int oyc = 2*oyp + c;
            int yi = 2*oyc + dy - 1;
            bool ok = okx && (oyc < 25) && (yi >= 0) && (yi < GD) && (z >= 1) && (z <= 50);
            uint4 v = make_uint4(0u,0u,0u,0u);
            if (ok) v = *(const uint4*)(y1 + (size_t)((b*GD + xi)*GD + yi)*3200 + cc*8 - 64);
            const u16* p = (const u16*)&v;
            u16 d8[8];
            #pragma unroll
            for (int j=0;j<8;j++) {
                int ci = sl*8 + j;
                d8[j] = ok ? f2bf(fmaxf(bf2f(p[j])*sc1[ci] + sh1[ci], 0.f)) : (u16)0;
            }
            *(uint4*)(in2 + (c*52 + z)*64 + ((sl ^ ((z>>1) & 7)) << 3)) = *(uint4*)d8;
        }
        {
            const u16* wsrc = wt2 + dxy*24576;
            #pragma unroll
            for (int i2 = 0; i2 < 12; ++i2) {
                int i = t + i2*256;
                *(uint4*)(w2s + i*8) = *(const uint4*)(wsrc + i*8);
            }
        }
        __syncthreads();
        #pragma unroll
        for (int dz = 0; dz < 3; ++dz) {
            #pragma unroll
            for (int kc = 0; kc < 2; ++kc) {
                bf16x8 a[2], bb[4];
                #pragma unroll
                for (int mf = 0; mf < 2; ++mf) {
                    int z = 2*(mf*16 + lo) + dz; z = (z > 51) ? 51 : z;
                    a[mf] = *(const bf16x8*)(in2 + (col*52 + z)*64 + (((kc*4 + hi) ^ ((z>>1) & 7)) << 3));
                }
                #pragma unroll
                for (int nf = 0; nf < 4; ++nf)
                    bb[nf] = *(const bf16x8*)(w2s + (((dz*2 + kc)*4 + hi)*128 + (nh*4 + nf)*16 + lo)*8);
                #pragma unroll
                for (int mf = 0; mf < 2; ++mf) {
                    #pragma unroll
                    for (int nf = 0; nf < 4; ++nf)
                        acc[mf][nf] = __builtin_amdgcn_mfma_f32_16x16x32_bf16(a[mf], bb[nf], acc[mf][nf], 0, 0, 0);
                }
            }
        }
    }
    __syncthreads();
    float* trans = (float*)pool;      // [2][128][25] f32 = 25600 B
    if (oy < 25) {
        #pragma unroll
        for (int nf = 0; nf < 4; ++nf) {
            float s = 0.f, q = 0.f;
            int co = (nh*4 + nf)*16 + lo;
            #pragma unroll
            for (int mf = 0; mf < 2; ++mf) {
                #pragma unroll
                for (int r = 0; r < 4; ++r) {
                    int o = mf*16 + hi*4 + r;
                    if (o < 25) {
                        float v = acc[mf][nf][r];
                        trans[(col*128 + co)*25 + o] = v;
                        s += v; q += v*v;
                    }
                }
            }
            atomicAdd(&red2[co], s);
            atomicAdd(&red2[128 + co], q);
        }
    }
    __syncthreads();
    if (t < 128) {
        atomicAdd(&stats[S2_SUM + t], red2[t]);
        atomicAdd(&stats[S2_SQ  + t], red2[128 + t]);
    }
    for (int i = t; i < 6400; i += 256) {
        int c = i / 3200; int r = i - c*3200;
        int co = r / 25;  int oz = r - co*25;
        int oyc = 2*oyp + c;
        if (oyc < 25)
            out[((size_t)(b*128 + co)*625 + ox*25 + oyc)*25 + oz] = trans[(c*128 + co)*25 + oz];
    }
}

// ---- BN2 + ReLU in place on d_out ----
__global__ void k_bnrelu2(float* __restrict__ out, const float* __restrict__ stats) {
    int idx = blockIdx.x*256 + threadIdx.x;
    if (idx >= 8000000) return;
    int co = (idx / 15625) & 127;
    float v = out[idx];
    out[idx] = fmaxf(v*stats[SC2 + co] + stats[SH2 + co], 0.f);
}

extern "C" void kernel_launch(void* const* d_in, const int* in_sizes, int n_in,
                              void* d_out, int out_size, void* d_ws, size_t ws_size,
                              hipStream_t stream) {
    const float* vf     = (const float*)d_in[0];
    const int*   coords = (const int*)  d_in[1];
    const float* W1 = (const float*)d_in[2];
    const float* b1 = (const float*)d_in[3];
    const float* W2 = (const float*)d_in[4];
    const float* b2 = (const float*)d_in[5];
    const float* W3 = (const float*)d_in[6];
    const float* b3 = (const float*)d_in[7];
    const float* k1 = (const float*)d_in[8];
    const float* g1 = (const float*)d_in[9];
    const float* be1= (const float*)d_in[10];
    const float* k2 = (const float*)d_in[11];
    const float* g2 = (const float*)d_in[12];
    const float* be2= (const float*)d_in[13];

    char* ws = (char*)d_ws;
    int*   owner = (int*)  (ws + OWNER_OFF);
    float* stats = (float*)(ws + STATS_OFF);
    u16*   wt1   = (u16*)  (ws + WT1_OFF);
    u16*   wt2   = (u16*)  (ws + WT2_OFF);
    u16*   vw2f  = (u16*)  (ws + VW2F_OFF);
    u16*   vw3f  = (u16*)  (ws + VW3F_OFF);
    u16*   grid  = (u16*)  (ws + GRID_OFF);
    u16*   y1    = (u16*)  (ws + Y1_OFF);
    float* out   = (float*)d_out;

    hipMemsetAsync(owner, 0xFF, (size_t)NB*CELLS*4, stream);
    hipMemsetAsync(stats, 0, 768*4, stream);
    hipMemsetAsync(grid, 0, (size_t)NB*GD*GD*PZ*128*2, stream);

    k_wt_transform<<<864, 256, 0, stream>>>(k1, k2, W2, W3, wt1, wt2, vw2f, vw3f);
    k_owner<<<(NB*NVOX+255)/256, 256, 0, stream>>>(coords, owner);
    k_vfe<<<NB*NVOX/4, 256, 0, stream>>>(vf, coords, W1, b1, b2, b3, vw2f, vw3f, owner, grid);
    k_conv1<<<dim3(GD,25,NB), 256, 0, stream>>>(grid, wt1, y1, stats);
    k_finalize<<<1, 64, 0, stream>>>(stats, g1, be1, 64, 500000.f, S1_SUM, SC1, SH1);
    k_conv2<<<dim3(25,13,NB), 256, 0, stream>>>(y1, wt2, stats, out);
    k_finalize<<<1, 128, 0, stream>>>(stats, g2, be2, 128, 62500.f, S2_SUM, SC2, SH2);
    k_bnrelu2<<<(8000000+255)/256, 256, 0, stream>>>(out, stats);
}

// Round 5
// 831.522 us; speedup vs baseline: 8.0483x; 1.0217x over previous
//
#include <hip/hip_runtime.h>

typedef unsigned short u16;
typedef unsigned int u32;
typedef __attribute__((ext_vector_type(8))) short bf16x8;
typedef __attribute__((ext_vector_type(4))) float f32x4;

#define NB 4
#define NVOX 8192
#define GD 50
#define PZ 52
#define CELLS 125000

// ---- workspace layout (bytes) ----
#define OWNER_OFF 0u            // int32[4*125000] = 2,000,000
#define STATS_OFF 2000000u      // f32[768]
#define WT1_OFF   2003072u      // bf16 27*64*128 frag-linear = 442,368
#define WT2_OFF   2445440u      // bf16 27*128*64 frag-linear = 442,368
#define VW2F_OFF  2887808u      // bf16 8*128*8  = 16,384 (W2^T frag-linear)
#define VW3F_OFF  2904192u      // bf16 16*128*8 = 32,768 (W3^T frag-linear)
#define GRID_OFF  2936960u      // bf16 4*50*50*52*128 = 133,120,000
#define Y1_OFF    136056960u    // bf16 4*50*50*50*64  =  64,000,000

#define S1_SUM 0
#define S1_SQ  64
#define SC1    128
#define SH1    192
#define S2_SUM 256
#define S2_SQ  384
#define SC2    512
#define SH2    640

__device__ __forceinline__ float bf2f(u16 v){ union{u32 u; float f;} x; x.u=((u32)v)<<16; return x.f; }
__device__ __forceinline__ u16 f2bf(float f){ union{u32 u; float f;} x; x.f=f; u32 r = x.u + 0x7fffu + ((x.u>>16)&1u); return (u16)(r>>16); }
__device__ __forceinline__ f32x4 fzero(){ f32x4 v; v[0]=0.f; v[1]=0.f; v[2]=0.f; v[3]=0.f; return v; }

// ---- weight re-layout ----
__global__ void k_wt_transform(const float* __restrict__ k1, const float* __restrict__ k2,
                               const float* __restrict__ W2, const float* __restrict__ W3,
                               u16* __restrict__ wt1, u16* __restrict__ wt2,
                               u16* __restrict__ vw2f, u16* __restrict__ vw3f) {
    int idx = blockIdx.x * 256 + threadIdx.x;
    if (idx < 221184) {
        {
            int j = idx & 7, co = (idx>>3)&63, kq = (idx>>9)&3, kc = (idx>>11)&3, s = idx>>13;
            int ci = kc*32 + kq*8 + j;
            wt1[idx] = f2bf(k1[(co*128 + ci)*27 + s]);
        }
        {
            int j = idx & 7, co = (idx>>3)&127, kq = (idx>>10)&3, kc = (idx>>12)&1, s = idx>>13;
            int ci = kc*32 + kq*8 + j;
            wt2[idx] = f2bf(k2[(co*64 + ci)*27 + s]);
        }
    }
    if (idx < 8192) {
        int j = idx & 7, n = (idx>>3)&127, q = idx>>10;
        vw2f[idx] = f2bf(W2[(q*8+j)*128 + n]);
    }
    if (idx < 16384) {
        int j = idx & 7, n = (idx>>3)&127, q = idx>>10;
        vw3f[idx] = f2bf(W3[(q*8+j)*128 + n]);
    }
}

// ---- duplicate resolution: last-write-wins == max n per cell ----
__global__ void k_owner(const int* __restrict__ coords, int* __restrict__ owner) {
    int v = blockIdx.x * 256 + threadIdx.x;
    if (v >= NB*NVOX) return;
    int b = v >> 13, n = v & (NVOX-1);
    int x = coords[v*3], y = coords[v*3+1], z = coords[v*3+2];
    atomicMax(&owner[b*CELLS + (x*GD + y)*GD + z], n);
}

// ---- VFE via MFMA: 4 voxels (128 points) per block, 4 waves ----
__global__ __launch_bounds__(256, 2) void k_vfe(
        const float* __restrict__ vf, const int* __restrict__ coords,
        const float* __restrict__ W1, const float* __restrict__ b1,
        const float* __restrict__ b2, const float* __restrict__ b3,
        const u16* __restrict__ vw2f, const u16* __restrict__ vw3f,
        const int* __restrict__ owner, u16* __restrict__ grid) {
    const int bid = blockIdx.x;
    const int t = threadIdx.x;
    const int w = t >> 6, lane = t & 63;
    const int lo = lane & 15, hi = lane >> 4;
    const int chgrp = w >> 1, pgrp = w & 1;

    __shared__ __align__(16) char pool[49152];
    u16* h1s = (u16*)pool;                 // [128][64] bf16 swizzled
    char* h2s = pool + 16384;              // [128][128] bf16 swizzled (byte-addressed)
    float* red = (float*)(pool + 16384);   // [4 vox][16 lo][128 ch] f32 (reuses h2s)

    bf16x8 wa2[2][4], wa3[4][4];
    #pragma unroll
    for (int kk = 0; kk < 2; ++kk)
        #pragma unroll
        for (int cf = 0; cf < 4; ++cf)
            wa2[kk][cf] = *(const bf16x8*)(vw2f + (((kk*4+hi)*128) + chgrp*64 + cf*16 + lo)*8);
    #pragma unroll
    for (int kk = 0; kk < 4; ++kk)
        #pragma unroll
        for (int cf = 0; cf < 4; ++cf)
            wa3[kk][cf] = *(const bf16x8*)(vw3f + (((kk*4+hi)*128) + chgrp*64 + cf*16 + lo)*8);
    f32x4 bb2[4];
    #pragma unroll
    for (int cf = 0; cf < 4; ++cf)
        bb2[cf] = *(const f32x4*)(b2 + chgrp*64 + cf*16 + hi*4);

    {
        const int pt = t & 127, C0 = (t >> 7) * 32;
        f32x4 xv0 = *(const f32x4*)(vf + (size_t)(bid*128 + pt)*8);
        f32x4 xv1 = *(const f32x4*)(vf + (size_t)(bid*128 + pt)*8 + 4);
        float x[8] = {xv0[0],xv0[1],xv0[2],xv0[3],xv1[0],xv1[1],xv1[2],xv1[3]};
        float h[32];
        #pragma unroll
        for (int c = 0; c < 32; ++c) h[c] = b1[C0 + c];
        #pragma unroll
        for (int k = 0; k < 8; ++k) {
            float xk = x[k];
            #pragma unroll
            for (int c = 0; c < 32; ++c) h[c] += xk * W1[k*64 + C0 + c];
        }
        #pragma unroll
        for (int c8 = 0; c8 < 4; ++c8) {
            u16 d8[8];
            #pragma unroll
            for (int j = 0; j < 8; ++j) d8[j] = f2bf(fmaxf(h[c8*8 + j], 0.f));
            int slot = ((C0 >> 3) + c8) ^ (pt & 7);
            *(uint4*)(h1s + pt*64 + slot*8) = *(uint4*)d8;
        }
    }
    __syncthreads();

    f32x4 acc2[4][4];
    #pragma unroll
    for (int cf = 0; cf < 4; ++cf)
        #pragma unroll
        for (int pf = 0; pf < 4; ++pf) acc2[cf][pf] = fzero();
    #pragma unroll
    for (int kk = 0; kk < 2; ++kk) {
        bf16x8 bh[4];
        #pragma unroll
        for (int pf = 0; pf < 4; ++pf) {
            int pt = pgrp*64 + pf*16 + lo;
            bh[pf] = *(const bf16x8*)(h1s + pt*64 + (((kk*4+hi) ^ (pt&7)) << 3));
        }
        #pragma unroll
        for (int cf = 0; cf < 4; ++cf)
            #pragma unroll
            for (int pf = 0; pf < 4; ++pf)
                acc2[cf][pf] = __builtin_amdgcn_mfma_f32_16x16x32_bf16(wa2[kk][cf], bh[pf], acc2[cf][pf], 0, 0, 0);
    }
    #pragma unroll
    for (int cf = 0; cf < 4; ++cf) {
        #pragma unroll
        for (int pf = 0; pf < 4; ++pf) {
            int pt = pgrp*64 + pf*16 + lo;
            float v0 = fmaxf(acc2[cf][pf][0] + bb2[cf][0], 0.f);
            float v1 = fmaxf(acc2[cf][pf][1] + bb2[cf][1], 0.f);
            float v2 = fmaxf(acc2[cf][pf][2] + bb2[cf][2], 0.f);
            float v3 = fmaxf(acc2[cf][pf][3] + bb2[cf][3], 0.f);
            uint2 d;
            d.x = (u32)f2bf(v0) | ((u32)f2bf(v1) << 16);
            d.y = (u32)f2bf(v2) | ((u32)f2bf(v3) << 16);
            int s = (chgrp*8 + cf*2 + (hi>>1)) ^ (pt & 15);
            *(uint2*)(h2s + pt*256 + s*16 + (hi&1)*8) = d;
        }
    }
    __syncthreads();

    f32x4 acc3[4][4];
    #pragma unroll
    for (int cf = 0; cf < 4; ++cf)
        #pragma unroll
        for (int pf = 0; pf < 4; ++pf) acc3[cf][pf] = fzero();
    #pragma unroll
    for (int kk = 0; kk < 4; ++kk) {
        bf16x8 bh[4];
        #pragma unroll
        for (int pf = 0; pf < 4; ++pf) {
            int pt = pgrp*64 + pf*16 + lo;
            bh[pf] = *(const bf16x8*)(h2s + pt*256 + (((kk*4+hi) ^ (pt&15)) << 4));
        }
        #pragma unroll
        for (int cf = 0; cf < 4; ++cf)
            #pragma unroll
            for (int pf = 0; pf < 4; ++pf)
                acc3[cf][pf] = __builtin_amdgcn_mfma_f32_16x16x32_bf16(wa3[kk][cf], bh[pf], acc3[cf][pf], 0, 0, 0);
    }
    __syncthreads();

    #pragma unroll
    for (int vox01 = 0; vox01 < 2; ++vox01) {
        int vv = pgrp*2 + vox01;
        #pragma unroll
        for (int cf = 0; cf < 4; ++cf) {
            f32x4 mx;
            #pragma unroll
            for (int r = 0; r < 4; ++r)
                mx[r] = fmaxf(acc3[cf][vox01*2][r], acc3[cf][vox01*2+1][r]);
            int s4 = (cf*4 + hi) ^ lo;
            *(f32x4*)(red + vv*2048 + lo*128 + chgrp*64 + s4*4) = mx;
        }
    }
    __syncthreads();

    #pragma unroll
    for (int half = 0; half < 2; ++half) {
        int vv = (t >> 7) + half*2;
        int ch = t & 127;
        int cq = (ch & 63) >> 2, e = ch & 3, cg = ch >> 6;
        float m = -3.0e38f;
        #pragma unroll
        for (int lo2 = 0; lo2 < 16; ++lo2)
            m = fmaxf(m, red[vv*2048 + lo2*128 + cg*64 + ((cq ^ lo2) << 2) + e]);
        int gv = bid*4 + vv;
        int b = gv >> 13, n = gv & (NVOX-1);
        int x = coords[gv*3], y = coords[gv*3+1], z = coords[gv*3+2];
        if (owner[b*CELLS + (x*GD + y)*GD + z] == n) {
            size_t gi = ((((size_t)b*GD + x)*GD + y)*PZ + (z+1))*128 + ch;
            grid[gi] = f2bf(m + b3[ch]);
        }
    }
}

// ---- B-frag loader: weights direct from global (L2-resident) to registers ----
__device__ __forceinline__ void load_b1(const u16* __restrict__ wt1, int s, int kc0,
                                        int hi, int lo, bf16x8 dst[2][4]) {
    #pragma unroll
    for (int kk = 0; kk < 2; ++kk)
        #pragma unroll
        for (int nf = 0; nf < 4; ++nf)
            dst[kk][nf] = *(const bf16x8*)(wt1 + (size_t)((s*4 + kc0 + kk)*4 + hi)*512 + (nf*16 + lo)*8);
}

// ---- conv1 via MFMA: 3x3x3, 128->64, stride 1, pad 1 ----
// Block = 4 oy columns (1 per wave), wave tile 64z x 64co (4mf x 4nf).
// A (input) from LDS, staged once per dx (6 columns). B (weights) streamed
// from global L2 into registers, double-buffered at kc-pair granularity.
__global__ __launch_bounds__(256, 2) void k_conv1(
        const u16* __restrict__ grid, const u16* __restrict__ wt1,
        u16* __restrict__ y1, float* __restrict__ stats) {
    const int ox = blockIdx.x, oyp = blockIdx.y, b = blockIdx.z;
    const int t = threadIdx.x;
    const int w = t >> 6, lane = t & 63;
    const int lo = lane & 15, hi = lane >> 4;
    const int oy = oyp*4 + w;

    __shared__ __align__(16) u16 in_s[6*52*128];   // 79,872 B, slot^=(z&15)
    __shared__ float red[128];
    if (t < 128) red[t] = 0.f;

    f32x4 acc[4][4];
    #pragma unroll
    for (int mf = 0; mf < 4; ++mf)
        #pragma unroll
        for (int nf = 0; nf < 4; ++nf) acc[mf][nf] = fzero();

    for (int dx = 0; dx < 3; ++dx) {
        int xi = ox + dx - 1;
        bool okx = (xi >= 0) && (xi < GD);
        __syncthreads();
        // stage 6 input columns yi = 4*oyp-1 .. 4*oyp+4
        #pragma unroll
        for (int c = 0; c < 6; ++c) {
            int yi = oyp*4 - 1 + c;
            bool ok = okx && (yi >= 0) && (yi < GD);
            const u16* src = grid + ((size_t)(b*GD + xi)*GD + yi)*(size_t)(PZ*128);
            for (int i = t; i < 832; i += 256) {
                int z = i >> 4, sl = i & 15;
                uint4 v = make_uint4(0u,0u,0u,0u);
                if (ok) v = *(const uint4*)(src + i*8);
                *(uint4*)(in_s + c*6656 + z*128 + ((sl ^ (z & 15)) << 3)) = v;
            }
        }
        __syncthreads();
        #pragma unroll
        for (int dy = 0; dy < 3; ++dy) {
            const int col = w + dy;
            const int s0 = (dx*3 + dy)*3;
            bf16x8 bb0[2][4], bb1[2][4];
            load_b1(wt1, s0, 0, hi, lo, bb0);
            #pragma unroll
            for (int hs = 0; hs < 6; ++hs) {
                const int dz = hs >> 1, kc0 = (hs & 1)*2;
                if (hs < 5) {
                    const int hs2 = hs + 1;
                    if (hs & 1) load_b1(wt1, s0 + (hs2 >> 1), (hs2 & 1)*2, hi, lo, bb0);
                    else        load_b1(wt1, s0 + (hs2 >> 1), (hs2 & 1)*2, hi, lo, bb1);
                }
                #pragma unroll
                for (int kk = 0; kk < 2; ++kk) {
                    const int kc = kc0 + kk;
                    bf16x8 a[4];
                    #pragma unroll
                    for (int mf = 0; mf < 4; ++mf) {
                        int z = mf*16 + lo + dz; z = (z > 51) ? 51 : z;
                        a[mf] = *(const bf16x8*)(in_s + col*6656 + z*128 + (((kc*4 + hi) ^ (z & 15)) << 3));
                    }
                    #pragma unroll
                    for (int mf = 0; mf < 4; ++mf) {
                        #pragma unroll
                        for (int nf = 0; nf < 4; ++nf) {
                            if (hs & 1)
                                acc[mf][nf] = __builtin_amdgcn_mfma_f32_16x16x32_bf16(a[mf], bb1[kk][nf], acc[mf][nf], 0, 0, 0);
                            else
                                acc[mf][nf] = __builtin_amdgcn_mfma_f32_16x16x32_bf16(a[mf], bb0[kk][nf], acc[mf][nf], 0, 0, 0);
                        }
                    }
                }
            }
        }
    }
    // epilogue: store y1 + stats partials
    if (oy < GD) {
        const size_t colbase = ((size_t)(b*GD + ox)*GD + oy)*50;
        float s[4] = {0.f,0.f,0.f,0.f}, q[4] = {0.f,0.f,0.f,0.f};
        #pragma unroll
        for (int mf = 0; mf < 4; ++mf) {
            #pragma unroll
            for (int r = 0; r < 4; ++r) {
                int o = mf*16 + hi*4 + r;
                if (o < 50) {
                    #pragma unroll
                    for (int nf = 0; nf < 4; ++nf) {
                        float v = acc[mf][nf][r];
                        y1[(colbase + o)*64 + nf*16 + lo] = f2bf(v);
                        s[nf] += v; q[nf] += v*v;
                    }
                }
            }
        }
        #pragma unroll
        for (int nf = 0; nf < 4; ++nf) {
            atomicAdd(&red[nf*16 + lo], s[nf]);
            atomicAdd(&red[64 + nf*16 + lo], q[nf]);
        }
    }
    __syncthreads();
    if (t < 64) {
        atomicAdd(&stats[S1_SUM + t], red[t]);
        atomicAdd(&stats[S1_SQ  + t], red[64 + t]);
    }
}

// ---- BN finalize ----
__global__ void k_finalize(float* __restrict__ stats, const float* __restrict__ g,
                           const float* __restrict__ be, int C, float cnt,
                           int st_off, int sc_off, int sh_off) {
    int t = threadIdx.x;
    if (t < C) {
        float mean = stats[st_off + t] / cnt;
        float var  = stats[st_off + C + t] / cnt - mean*mean;
        float inv  = rsqrtf(var + 1e-5f);
        stats[sc_off + t] = g[t]*inv;
        stats[sh_off + t] = be[t] - mean*g[t]*inv;
    }
}

// ---- conv2 via MFMA: 3x3x3, 64->128, stride 2, pad 1; BN1+ReLU fused in staging ----
__global__ __launch_bounds__(256) void k_conv2(
        const u16* __restrict__ y1, const u16* __restrict__ wt2,
        float* __restrict__ stats, float* __restrict__ out) {
    const int ox = blockIdx.x, oyp = blockIdx.y, b = blockIdx.z;
    const int t = threadIdx.x;
    const int w = t >> 6, lane = t & 63;
    const int col = w >> 1, nh = w & 1, lo = lane & 15, hi = lane >> 4;

    __shared__ __align__(16) char pool[63488];
    u16* in2 = (u16*)pool;                // [2][52][64] bf16, slot^=((z>>1)&7)
    u16* w2s = (u16*)(pool + 13312);      // [24576] frag-linear
    float* red2 = (float*)(pool + 62464); // [256]
    red2[t] = 0.f;

    const float* sc1 = stats + SC1;
    const float* sh1 = stats + SH1;

    f32x4 acc[2][4];
    #pragma unroll
    for (int m=0;m<2;m++){ acc[m][0]=fzero(); acc[m][1]=fzero(); acc[m][2]=fzero(); acc[m][3]=fzero(); }

    const int oy = 2*oyp + col;
    for (int dxy = 0; dxy < 9; ++dxy) {
        int dx = dxy/3, dy = dxy - dx*3;
        int xi = 2*ox + dx - 1;
        bool okx = (xi >= 0) && (xi < GD);
        __syncthreads();
        for (int i = t; i < 832; i += 256) {
            int c = (i >= 416) ? 1 : 0;
            int cc = i - c*416;
            int z = cc >> 3, sl = cc & 7;
            int oyc = 2*oyp + c;
            int yi = 2*oyc + dy - 1;
            bool ok = okx && (oyc < 25) && (yi >= 0) && (yi < GD) && (z >= 1) && (z <= 50);
            uint4 v = make_uint4(0u,0u,0u,0u);
            if (ok) v = *(const uint4*)(y1 + (size_t)((b*GD + xi)*GD + yi)*3200 + cc*8 - 64);
            const u16* p = (const u16*)&v;
            u16 d8[8];
            #pragma unroll
            for (int j=0;j<8;j++) {
                int ci = sl*8 + j;
                d8[j] = ok ? f2bf(fmaxf(bf2f(p[j])*sc1[ci] + sh1[ci], 0.f)) : (u16)0;
            }
            *(uint4*)(in2 + (c*52 + z)*64 + ((sl ^ ((z>>1) & 7)) << 3)) = *(uint4*)d8;
        }
        {
            const u16* wsrc = wt2 + dxy*24576;
            #pragma unroll
            for (int i2 = 0; i2 < 12; ++i2) {
                int i = t + i2*256;
                *(uint4*)(w2s + i*8) = *(const uint4*)(wsrc + i*8);
            }
        }
        __syncthreads();
        #pragma unroll
        for (int dz = 0; dz < 3; ++dz) {
            #pragma unroll
            for (int kc = 0; kc < 2; ++kc) {
                bf16x8 a[2], bb[4];
                #pragma unroll
                for (int mf = 0; mf < 2; ++mf) {
                    int z = 2*(mf*16 + lo) + dz; z = (z > 51) ? 51 : z;
                    a[mf] = *(const bf16x8*)(in2 + (col*52 + z)*64 + (((kc*4 + hi) ^ ((z>>1) & 7)) << 3));
                }
                #pragma unroll
                for (int nf = 0; nf < 4; ++nf)
                    bb[nf] = *(const bf16x8*)(w2s + (((dz*2 + kc)*4 + hi)*128 + (nh*4 + nf)*16 + lo)*8);
                #pragma unroll
                for (int mf = 0; mf < 2; ++mf) {
                    #pragma unroll
                    for (int nf = 0; nf < 4; ++nf)
                        acc[mf][nf] = __builtin_amdgcn_mfma_f32_16x16x32_bf16(a[mf], bb[nf], acc[mf][nf], 0, 0, 0);
                }
            }
        }
    }
    __syncthreads();
    float* trans = (float*)pool;      // [2][128][25] f32 = 25600 B
    if (oy < 25) {
        #pragma unroll
        for (int nf = 0; nf < 4; ++nf) {
            float s = 0.f, q = 0.f;
            int co = (nh*4 + nf)*16 + lo;
            #pragma unroll
            for (int mf = 0; mf < 2; ++mf) {
                #pragma unroll
                for (int r = 0; r < 4; ++r) {
                    int o = mf*16 + hi*4 + r;
                    if (o < 25) {
                        float v = acc[mf][nf][r];
                        trans[(col*128 + co)*25 + o] = v;
                        s += v; q += v*v;
                    }
                }
            }
            atomicAdd(&red2[co], s);
            atomicAdd(&red2[128 + co], q);
        }
    }
    __syncthreads();
    if (t < 128) {
        atomicAdd(&stats[S2_SUM + t], red2[t]);
        atomicAdd(&stats[S2_SQ  + t], red2[128 + t]);
    }
    for (int i = t; i < 6400; i += 256) {
        int c = i / 3200; int r = i - c*3200;
        int co = r / 25;  int oz = r - co*25;
        int oyc = 2*oyp + c;
        if (oyc < 25)
            out[((size_t)(b*128 + co)*625 + ox*25 + oyc)*25 + oz] = trans[(c*128 + co)*25 + oz];
    }
}

// ---- BN2 + ReLU in place on d_out ----
__global__ void k_bnrelu2(float* __restrict__ out, const float* __restrict__ stats) {
    int idx = blockIdx.x*256 + threadIdx.x;
    if (idx >= 8000000) return;
    int co = (idx / 15625) & 127;
    float v = out[idx];
    out[idx] = fmaxf(v*stats[SC2 + co] + stats[SH2 + co], 0.f);
}

extern "C" void kernel_launch(void* const* d_in, const int* in_sizes, int n_in,
                              void* d_out, int out_size, void* d_ws, size_t ws_size,
                              hipStream_t stream) {
    const float* vf     = (const float*)d_in[0];
    const int*   coords = (const int*)  d_in[1];
    const float* W1 = (const float*)d_in[2];
    const float* b1 = (const float*)d_in[3];
    const float* W2 = (const float*)d_in[4];
    const float* b2 = (const float*)d_in[5];
    const float* W3 = (const float*)d_in[6];
    const float* b3 = (const float*)d_in[7];
    const float* k1 = (const float*)d_in[8];
    const float* g1 = (const float*)d_in[9];
    const float* be1= (const float*)d_in[10];
    const float* k2 = (const float*)d_in[11];
    const float* g2 = (const float*)d_in[12];
    const float* be2= (const float*)d_in[13];

    char* ws = (char*)d_ws;
    int*   owner = (int*)  (ws + OWNER_OFF);
    float* stats = (float*)(ws + STATS_OFF);
    u16*   wt1   = (u16*)  (ws + WT1_OFF);
    u16*   wt2   = (u16*)  (ws + WT2_OFF);
    u16*   vw2f  = (u16*)  (ws + VW2F_OFF);
    u16*   vw3f  = (u16*)  (ws + VW3F_OFF);
    u16*   grid  = (u16*)  (ws + GRID_OFF);
    u16*   y1    = (u16*)  (ws + Y1_OFF);
    float* out   = (float*)d_out;

    hipMemsetAsync(owner, 0xFF, (size_t)NB*CELLS*4, stream);
    hipMemsetAsync(stats, 0, 768*4, stream);
    hipMemsetAsync(grid, 0, (size_t)NB*GD*GD*PZ*128*2, stream);

    k_wt_transform<<<864, 256, 0, stream>>>(k1, k2, W2, W3, wt1, wt2, vw2f, vw3f);
    k_owner<<<(NB*NVOX+255)/256, 256, 0, stream>>>(coords, owner);
    k_vfe<<<NB*NVOX/4, 256, 0, stream>>>(vf, coords, W1, b1, b2, b3, vw2f, vw3f, owner, grid);
    k_conv1<<<dim3(GD,13,NB), 256, 0, stream>>>(grid, wt1, y1, stats);
    k_finalize<<<1, 64, 0, stream>>>(stats, g1, be1, 64, 500000.f, S1_SUM, SC1, SH1);
    k_conv2<<<dim3(25,13,NB), 256, 0, stream>>>(y1, wt2, stats, out);
    k_finalize<<<1, 128, 0, stream>>>(stats, g2, be2, 128, 62500.f, S2_SUM, SC2, SH2);
    k_bnrelu2<<<(8000000+255)/256, 256, 0, stream>>>(out, stats);
}